// Round 8
// baseline (858.014 us; speedup 1.0000x reference)
//
#include <hip/hip_runtime.h>
#include <math.h>

#define R_ 512
#define C_ 512
#define E_ 256
#define H_ 8
#define D_ 32
#define RC_ (R_*C_)   // 262144
#define RP 136        // repack pitch (ushorts)

typedef __attribute__((ext_vector_type(8))) short bf16x8;
typedef __attribute__((ext_vector_type(4))) float f32x4;
typedef __attribute__((ext_vector_type(16))) float f32x16;

__device__ __forceinline__ ushort f2bf(float f) {
    union { float f; unsigned u; } v; v.f = f;
    unsigned r = v.u + 0x7FFFu + ((v.u >> 16) & 1u);   // RNE
    return (ushort)(r >> 16);
}
__device__ __forceinline__ float bf2f(ushort u) {
    union { unsigned u; float f; } v; v.u = ((unsigned)u) << 16;
    return v.f;
}

// 16B global->LDS direct copy (lane-linear dest), fallback = reg staging.
__device__ __forceinline__ void gll16(const ushort* g, ushort* l) {
#if __has_builtin(__builtin_amdgcn_global_load_lds)
    __builtin_amdgcn_global_load_lds(
        (const __attribute__((address_space(1))) unsigned*)(unsigned long long)g,
        (__attribute__((address_space(3))) unsigned*)(unsigned)(unsigned long long)l,
        16, 0, 0);
#else
    *(uint4*)l = *(const uint4*)g;
#endif
}

// Stage one 16B chunk f of a [rows][32-ushort] tile.  Source slot is XOR-
// swizzled with (row>>1)&3 (bank-relevant key for 64B rows — verified in r7:
// conflicts 1.6e7 -> 3.7e6).  LDS dest stays lane-linear; read side applies
// the same involution.
#define SCH(gbase, stride, lds, f)                                               \
    gll16((gbase) + (size_t)((f) >> 2) * (stride)                                \
              + (((((f) & 3) ^ ((((f) >> 2) >> 1) & 3))) << 3),                  \
          (lds) + (f) * 8)

// Per-wave 64x64 output, 16x16x32 bf16 MFMA, K=32 per step, 32-ushort rows.
#define PREAMBLE(WM, WN)                                \
    const int t = threadIdx.x;                          \
    const int wid = t >> 6, l = t & 63;                 \
    const int wm = (WM), wn = (WN);                     \
    const int l15 = l & 15, lhi = l >> 4;               \
    const int swz8 = (lhi ^ ((l15 >> 1) & 3)) * 8;      \
    f32x4 acc[4][4];                                    \
    _Pragma("unroll")                                   \
    for (int a_ = 0; a_ < 4; ++a_)                      \
        _Pragma("unroll")                               \
        for (int b_ = 0; b_ < 4; ++b_)                  \
            acc[a_][b_] = (f32x4){0.f, 0.f, 0.f, 0.f};

#define MFMA_STEP(As, Bs)                                                        \
    {                                                                            \
        bf16x8 af_[4], bf_[4];                                                   \
        _Pragma("unroll")                                                        \
        for (int f_ = 0; f_ < 4; ++f_) {                                         \
            af_[f_] = *(const bf16x8*)((As) + (wm*64 + f_*16 + l15)*32 + swz8);  \
            bf_[f_] = *(const bf16x8*)((Bs) + (wn*64 + f_*16 + l15)*32 + swz8);  \
        }                                                                        \
        _Pragma("unroll")                                                        \
        for (int m_ = 0; m_ < 4; ++m_)                                           \
            _Pragma("unroll")                                                    \
            for (int n_ = 0; n_ < 4; ++n_)                                       \
                acc[m_][n_] = __builtin_amdgcn_mfma_f32_16x16x32_bf16(           \
                    af_[m_], bf_[n_], acc[m_][n_], 0, 0, 0);                     \
    }

// Double-buffered K-loop, __syncthreads-fenced (safe).  NIT even, >= 4.
#define DBUF(STG, NIT)                                                           \
    STG(0, A0, B0); __syncthreads();                                             \
    for (int itp = 0; itp < (NIT)/2 - 1; ++itp) {                                \
        STG(2*itp+1, A1, B1); MFMA_STEP(A0, B0); __syncthreads();                \
        STG(2*itp+2, A0, B0); MFMA_STEP(A1, B1); __syncthreads();                \
    }                                                                            \
    STG((NIT)-1, A1, B1); MFMA_STEP(A0, B0); __syncthreads();                    \
    MFMA_STEP(A1, B1); __syncthreads();

// ---------------------------------------------------------------------------
// x fp32 -> bf16, once.
// ---------------------------------------------------------------------------
__global__ __launch_bounds__(256) void convert_x(
    const float* __restrict__ x, ushort* __restrict__ xb)
{
    const size_t blk = (size_t)blockIdx.x * 4096;
    #pragma unroll
    for (int c = 0; c < 4; ++c) {
        const size_t s = blk + ((size_t)threadIdx.x + 256 * c) * 4;
        float4 a = *(const float4*)(x + s);
        ushort o[4] = {f2bf(a.x), f2bf(a.y), f2bf(a.z), f2bf(a.w)};
        *(uint2*)(xb + s) = *(uint2*)o;
    }
}

// ---------------------------------------------------------------------------
// Weights -> n-major bf16.
// ---------------------------------------------------------------------------
__global__ __launch_bounds__(256) void convert_w(
    const float* __restrict__ Wq, const float* __restrict__ Wk,
    const float* __restrict__ Wv, const float* __restrict__ Wo,
    ushort* __restrict__ WTqkv, ushort* __restrict__ WoT)
{
    const int id = blockIdx.x;      // 0..1023
    const int matn = id >> 8;
    const int n = id & 255;
    const int k = threadIdx.x;
    const float* W = (matn == 0) ? Wq : (matn == 1) ? Wk : (matn == 2) ? Wv : Wo;
    ushort v = f2bf(W[(size_t)k * E_ + n]);
    if (matn < 3) WTqkv[((size_t)matn * E_ + n) * E_ + k] = v;
    else          WoT[(size_t)n * E_ + k] = v;
}

// ---------------------------------------------------------------------------
// Fused QKV projection — DIRECT-TO-REGISTER fragments, no K-loop LDS/barriers.
// 12288 blocks x 256 thr (4 waves 2x2, 64x64 out each), 32x32x16 bf16 MFMA.
// Lane l loads A row (l&31), k-slot (l>>5)*8 as one dwordx4 — identical
// pattern for A and B so intra-fragment k-permutation cancels.  4-deep
// register prefetch; L1/L2 serve the shared panels.  Epilogue repacks via
// LDS as before (only sync point).  C/D map (m74/m101): col=lane&31,
// row=(reg&3)+8*(reg>>2)+4*(lane>>5).
// ---------------------------------------------------------------------------
__global__ __launch_bounds__(256) void qkv_mfma(
    const ushort* __restrict__ xb, const ushort* __restrict__ WT,
    const float* __restrict__ bq, const float* __restrict__ bk,
    const float* __restrict__ bv, const float* __restrict__ mask,
    ushort* __restrict__ qb, ushort* __restrict__ kb, ushort* __restrict__ vb)
{
    __shared__ __align__(16) ushort S[128 * RP];   // epilogue repack only
    const int id = ((blockIdx.x & 7) * 1536) + (blockIdx.x >> 3);
    const int nt = id % 6;
    const int rc0 = (id / 6) * 128;
    const int t = threadIdx.x;
    const int wid = t >> 6, l = t & 63;
    const int wm = wid >> 1, wn = wid & 1;
    const int l31 = l & 31, lh = l >> 5;

    const ushort* Abase = xb + (size_t)(rc0 + wm * 64 + l31) * E_ + lh * 8;
    const ushort* Bbase = WT + (size_t)(nt * 128 + wn * 64 + l31) * E_ + lh * 8;

#define LDA(ks, mb) (*(const bf16x8*)(Abase + (size_t)(mb) * 32 * E_ + (ks) * 16))
#define LDB(ks, nb) (*(const bf16x8*)(Bbase + (size_t)(nb) * 32 * E_ + (ks) * 16))

    f32x16 acc[2][2];
    #pragma unroll
    for (int mb = 0; mb < 2; ++mb)
        #pragma unroll
        for (int nb = 0; nb < 2; ++nb)
            #pragma unroll
            for (int r = 0; r < 16; ++r) acc[mb][nb][r] = 0.f;

    bf16x8 aF[4][2], bF[4][2];
    #pragma unroll
    for (int p = 0; p < 4; ++p) {
        aF[p][0] = LDA(p, 0); aF[p][1] = LDA(p, 1);
        bF[p][0] = LDB(p, 0); bF[p][1] = LDB(p, 1);
    }

    #pragma unroll
    for (int ks = 0; ks < 16; ++ks) {
        const int sl = ks & 3;
        #pragma unroll
        for (int mb = 0; mb < 2; ++mb)
            #pragma unroll
            for (int nb = 0; nb < 2; ++nb)
                acc[mb][nb] = __builtin_amdgcn_mfma_f32_32x32x16_bf16(
                    aF[sl][mb], bF[sl][nb], acc[mb][nb], 0, 0, 0);
        if (ks < 12) {
            aF[sl][0] = LDA(ks + 4, 0); aF[sl][1] = LDA(ks + 4, 1);
            bF[sl][0] = LDB(ks + 4, 0); bF[sl][1] = LDB(ks + 4, 1);
        }
    }

    const int proj = nt >> 1;
    const float* bias = (proj == 0) ? bq : (proj == 1) ? bk : bv;
    float bvv[2];
    #pragma unroll
    for (int nb = 0; nb < 2; ++nb)
        bvv[nb] = bias[(nt * 128 + wn * 64 + nb * 32 + l31) & 255];

    // repack: q/k as [m(row)][n(col)], v transposed
    #pragma unroll
    for (int mb = 0; mb < 2; ++mb)
        #pragma unroll
        for (int nb = 0; nb < 2; ++nb)
            #pragma unroll
            for (int rg = 0; rg < 16; ++rg) {
                const int m = wm * 64 + mb * 32 + (rg & 3) + 8 * (rg >> 2) + 4 * lh;
                const int n = wn * 64 + nb * 32 + l31;
                const ushort val = f2bf(acc[mb][nb][rg] + bvv[nb]);
                if (proj < 2) S[m * RP + n] = val;
                else          S[n * RP + m] = val;
            }
    __syncthreads();

    const int r = rc0 >> 9, c0 = rc0 & 511;
    if (proj < 2) {
        ushort* dst = (proj == 0) ? qb : kb;
        #pragma unroll
        for (int c = 0; c < 8; ++c) {
            const int idx = t + 256 * c;
            const int mrow = idx >> 4, ne = (idx & 15) * 8;
            uint4 w = *(const uint4*)(S + mrow * RP + ne);
            if (proj == 0) {   // q: * 1/128 * (1-mask)
                const float sk = 0.0078125f * (1.0f - mask[rc0 + mrow]);
                ushort* ws = (ushort*)&w;
                #pragma unroll
                for (int jj = 0; jj < 8; ++jj) ws[jj] = f2bf(bf2f(ws[jj]) * sk);
            }
            const int e = (nt & 1) * 128 + ne, h = e >> 5, d = e & 31;
            *(uint4*)(dst + ((((size_t)h * R_ + r) * C_) + c0 + mrow) * D_ + d) = w;
        }
    } else {
        #pragma unroll
        for (int c = 0; c < 8; ++c) {
            const int idx = t + 256 * c;
            const int nrow = idx >> 4, m0 = (idx & 15) * 8;
            uint4 w = *(const uint4*)(S + nrow * RP + m0);
            const int e = (nt & 1) * 128 + nrow, h = e >> 5, d = e & 31;
            *(uint4*)(vb + (((size_t)h * R_ + r) * D_ + d) * C_ + c0 + m0) = w;
        }
    }
}

// ---------------------------------------------------------------------------
// Attention logits.  128x128 tile, 256 threads, K split 8-way (1024 blocks).
// ---------------------------------------------------------------------------
__global__ __launch_bounds__(256) void logits_mfma(
    const ushort* __restrict__ qb, const ushort* __restrict__ kb,
    float* __restrict__ partial)
{
    __shared__ __align__(16) ushort S[16384];
    ushort* A0 = S;
    ushort* B0 = S + 4096;
    ushort* A1 = S + 8192;
    ushort* B1 = S + 12288;
    const int id = ((blockIdx.x & 7) * 128) + (blockIdx.x >> 3);
    const int sub = id & 15;
    const int j0 = (sub & 3) * 128;         // j fastest: 4 blocks share q panel
    const int i0 = (sub >> 2) * 128;
    const int hks = id >> 4;                // 0..63
    const int h = hks >> 3, ks = hks & 7;
    PREAMBLE(wid >> 1, wid & 1);

    const ushort* Ab = qb + (((size_t)h * R_ + ks * 64) * C_ + i0) * D_;
    const ushort* Bb = kb + (((size_t)h * R_ + ks * 64) * C_ + j0) * D_;

#define LSTG(i, Abuf, Bbuf) {                                   \
    const ushort* Ai = Ab + (size_t)(i) * (C_ * D_);            \
    const ushort* Bi = Bb + (size_t)(i) * (C_ * D_);            \
    SCH(Ai, D_, Abuf, t); SCH(Ai, D_, Abuf, t + 256);           \
    SCH(Bi, D_, Bbuf, t); SCH(Bi, D_, Bbuf, t + 256); }
    DBUF(LSTG, 64);

    float* dst = partial + ((size_t)ks * H_ + h) * C_ * C_;
    #pragma unroll
    for (int fm = 0; fm < 4; ++fm)
        #pragma unroll
        for (int rg = 0; rg < 4; ++rg) {
            const int i = i0 + wm * 64 + fm * 16 + lhi * 4 + rg;
            #pragma unroll
            for (int fn = 0; fn < 4; ++fn) {
                const int j = j0 + wn * 64 + fn * 16 + l15;
                dst[(size_t)i * C_ + j] = acc[fm][fn][rg];
            }
        }
}

// ---------------------------------------------------------------------------
// Sum 8 K-split partials + i-axis mask + softmax over j.
// ---------------------------------------------------------------------------
__global__ __launch_bounds__(256) void softmax_kernel(
    const float* __restrict__ partial, const float* __restrict__ mask,
    float* __restrict__ probs, ushort* __restrict__ Pb)
{
    const int hi = blockIdx.x;
    const int i = hi & 511;
    const int t = threadIdx.x;
    const size_t base = (size_t)hi * C_;
    const size_t stride = (size_t)H_ * C_ * C_;
    float v0 = 0.f, v1 = 0.f;
    #pragma unroll
    for (int ksp = 0; ksp < 8; ++ksp) {
        v0 += partial[ksp * stride + base + t];
        v1 += partial[ksp * stride + base + t + 256];
    }
    const float mi = mask[i];
    const float keep = 1.0f - mi;
    v0 = v0 * keep + mi * (-10000.0f);
    v1 = v1 * keep + mi * (-10000.0f);

    float m = fmaxf(v0, v1);
    #pragma unroll
    for (int off = 32; off > 0; off >>= 1) m = fmaxf(m, __shfl_xor(m, off));
    __shared__ float red[4];
    if ((t & 63) == 0) red[t >> 6] = m;
    __syncthreads();
    m = fmaxf(fmaxf(red[0], red[1]), fmaxf(red[2], red[3]));

    const float e0 = expf(v0 - m), e1 = expf(v1 - m);
    float s = e0 + e1;
    #pragma unroll
    for (int off = 32; off > 0; off >>= 1) s += __shfl_xor(s, off);
    __syncthreads();
    if ((t & 63) == 0) red[t >> 6] = s;
    __syncthreads();
    s = red[0] + red[1] + red[2] + red[3];

    const float inv = 1.0f / s;
    const float p0 = e0 * inv, p1 = e1 * inv;
    probs[base + t] = p0;
    probs[base + t + 256] = p1;
    Pb[base + t] = f2bf(p0);
    Pb[base + t + 256] = f2bf(p1);
}

// ---------------------------------------------------------------------------
// Context.  128x128 tile, 256 threads, 4096 blocks (one head per XCD).
// ---------------------------------------------------------------------------
__global__ __launch_bounds__(256) void context_mfma(
    const ushort* __restrict__ Pb, const ushort* __restrict__ vb,
    ushort* __restrict__ ctxb)
{
    __shared__ __align__(16) ushort S[128 * RP];
    ushort* A0 = S;
    ushort* B0 = S + 4096;
    ushort* A1 = S + 8192;
    ushort* B1 = S + 12288;
    const int id = ((blockIdx.x & 7) * 512) + (blockIdx.x >> 3);
    const int i0 = (id & 3) * 128;          // i fastest: 4 blocks share vb panel
    const int n0 = ((id >> 2) & 127) * 128;
    const int h = id >> 9;
    PREAMBLE(wid >> 1, wid & 1);

    const ushort* Ab = Pb + ((size_t)h * C_ + i0) * C_;
    const ushort* Bb = vb + ((size_t)h * R_ * D_ + n0) * C_;

#define CSTG(i, Abuf, Bbuf) {                                   \
    const ushort* Ai = Ab + (i) * 32;                           \
    const ushort* Bi = Bb + (i) * 32;                           \
    SCH(Ai, C_, Abuf, t); SCH(Ai, C_, Abuf, t + 256);           \
    SCH(Bi, C_, Bbuf, t); SCH(Bi, C_, Bbuf, t + 256); }
    DBUF(CSTG, 16);

    #pragma unroll
    for (int fm = 0; fm < 4; ++fm)
        #pragma unroll
        for (int fn = 0; fn < 4; ++fn)
            #pragma unroll
            for (int rg = 0; rg < 4; ++rg) {
                const int m = wm * 64 + fm * 16 + lhi * 4 + rg;
                const int n = wn * 64 + fn * 16 + l15;
                S[m * RP + n] = f2bf(acc[fm][fn][rg]);
            }
    __syncthreads();

    #pragma unroll
    for (int c = 0; c < 8; ++c) {
        const int idx = t + 256 * c;
        const int mrow = idx >> 4, nl = (idx & 15) * 8;
        uint4 w = *(const uint4*)(S + mrow * RP + nl);
        const int n = n0 + nl;
        const int rr = n >> 5, d = n & 31;
        const size_t rc = (size_t)rr * C_ + i0 + mrow;
        *(uint4*)(ctxb + rc * E_ + h * D_ + d) = w;
    }
}

// ---------------------------------------------------------------------------
// Output projection.  128x128 tile, 256 threads, 4096 blocks, fp32 out.
// ---------------------------------------------------------------------------
__global__ __launch_bounds__(256) void out_proj_mfma(
    const ushort* __restrict__ ctxb, const ushort* __restrict__ WoT,
    const float* __restrict__ bo, float* __restrict__ out)
{
    __shared__ __align__(16) ushort S[128 * RP];
    ushort* A0 = S;
    ushort* B0 = S + 4096;
    ushort* A1 = S + 8192;
    ushort* B1 = S + 12288;
    float* Sf = (float*)S;                  // 128 x 68 fp32 repack
    const int id = ((blockIdx.x & 7) * 512) + (blockIdx.x >> 3);
    const int n0 = (id & 1) * 128;
    const int rc0 = (id >> 1) * 128;
    PREAMBLE(wid >> 1, wid & 1);

    const ushort* Ab = ctxb + (size_t)rc0 * E_;
    const ushort* Bb = WoT + (size_t)n0 * E_;

#define OSTG(i, Abuf, Bbuf) {                                   \
    const ushort* Ai = Ab + (i) * 32;                           \
    const ushort* Bi = Bb + (i) * 32;                           \
    SCH(Ai, E_, Abuf, t); SCH(Ai, E_, Abuf, t + 256);           \
    SCH(Bi, E_, Bbuf, t); SCH(Bi, E_, Bbuf, t + 256); }
    DBUF(OSTG, 8);

    float bvv[4];
    #pragma unroll
    for (int fn = 0; fn < 4; ++fn)
        bvv[fn] = bo[n0 + wn * 64 + fn * 16 + l15];

    #pragma unroll
    for (int p = 0; p < 2; ++p) {
        #pragma unroll
        for (int fm = 0; fm < 4; ++fm)
            #pragma unroll
            for (int fh = 0; fh < 2; ++fh) {
                const int fn = 2 * p + fh;
                #pragma unroll
                for (int rg = 0; rg < 4; ++rg) {
                    const int m = wm * 64 + fm * 16 + lhi * 4 + rg;
                    const int s = wn * 32 + fh * 16 + l15;
                    Sf[m * 68 + s] = acc[fm][fn][rg] + bvv[fn];
                }
            }
        __syncthreads();
        #pragma unroll
        for (int c = 0; c < 8; ++c) {
            const int idx = t + 256 * c;
            const int row = idx >> 4, s0 = (idx & 15) * 4;
            float4 w = *(const float4*)(Sf + row * 68 + s0);
            const int ncol = n0 + (s0 >> 5) * 64 + (2 * p + ((s0 >> 4) & 1)) * 16 + (s0 & 15);
            *(float4*)(out + ((size_t)rc0 + row) * E_ + ncol) = w;
        }
        __syncthreads();
    }
}

// ---------------------------------------------------------------------------
extern "C" void kernel_launch(void* const* d_in, const int* in_sizes, int n_in,
                              void* d_out, int out_size, void* d_ws, size_t ws_size,
                              hipStream_t stream)
{
    const float* x    = (const float*)d_in[0];
    const float* mask = (const float*)d_in[1];
    const float* Wq   = (const float*)d_in[2];
    const float* bq   = (const float*)d_in[3];
    const float* Wk   = (const float*)d_in[4];
    const float* bk   = (const float*)d_in[5];
    const float* Wv   = (const float*)d_in[6];
    const float* bv   = (const float*)d_in[7];
    const float* Wo   = (const float*)d_in[8];
    const float* bo   = (const float*)d_in[9];

    float* out   = (float*)d_out;                       // [R,C,E] fp32
    float* probs = out + (size_t)RC_ * E_;              // [H,C,C] fp32

    char* ws = (char*)d_ws;
    ushort* qb      = (ushort*)(ws);                    // 128 MB  [h][r][c][d]
    ushort* kb      = (ushort*)(ws + 134217728ull);     // 128 MB  [h][r][c][d]
    ushort* vb      = (ushort*)(ws + 268435456ull);     // 128 MB  [h][r][d][c]
    ushort* ctxb    = (ushort*)(ws + 402653184ull);     // 128 MB  [rc][e]
    float*  partial = (float*)(ws + 536870912ull);      // 64 MB   [8][h][i][j]
    ushort* Pb      = (ushort*)(ws + 603979776ull);     // 4 MB    [h][i][j]
    ushort* WTqkv   = (ushort*)(ws + 608174080ull);     // 384 KB
    ushort* WoT     = (ushort*)(ws + 608567296ull);     // 128 KB
    ushort* xb      = (ushort*)(ws + 608700416ull);     // 128 MB  [rc][e]

    convert_x<<<16384, 256, 0, stream>>>(x, xb);
    convert_w<<<1024, 256, 0, stream>>>(Wq, Wk, Wv, Wo, WTqkv, WoT);
    qkv_mfma<<<12288, 256, 0, stream>>>(xb, WTqkv, bq, bk, bv, mask, qb, kb, vb);
    logits_mfma<<<1024, 256, 0, stream>>>(qb, kb, partial);
    softmax_kernel<<<4096, 256, 0, stream>>>(partial, mask, probs, Pb);
    context_mfma<<<4096, 256, 0, stream>>>(Pb, vb, ctxb);
    out_proj_mfma<<<4096, 256, 0, stream>>>(ctxb, WoT, bo, out);
}

// Round 9
// 733.119 us; speedup vs baseline: 1.1704x; 1.1704x over previous
//
#include <hip/hip_runtime.h>
#include <math.h>

#define R_ 512
#define C_ 512
#define E_ 256
#define H_ 8
#define D_ 32
#define RC_ (R_*C_)   // 262144
#define RP 136        // repack pitch (ushorts)

typedef __attribute__((ext_vector_type(8))) short bf16x8;
typedef __attribute__((ext_vector_type(4))) float f32x4;

__device__ __forceinline__ ushort f2bf(float f) {
    union { float f; unsigned u; } v; v.f = f;
    unsigned r = v.u + 0x7FFFu + ((v.u >> 16) & 1u);   // RNE
    return (ushort)(r >> 16);
}
__device__ __forceinline__ float bf2f(ushort u) {
    union { unsigned u; float f; } v; v.u = ((unsigned)u) << 16;
    return v.f;
}

// 16B global->LDS direct copy (lane-linear dest), fallback = reg staging.
__device__ __forceinline__ void gll16(const ushort* g, ushort* l) {
#if __has_builtin(__builtin_amdgcn_global_load_lds)
    __builtin_amdgcn_global_load_lds(
        (const __attribute__((address_space(1))) unsigned*)(unsigned long long)g,
        (__attribute__((address_space(3))) unsigned*)(unsigned)(unsigned long long)l,
        16, 0, 0);
#else
    *(uint4*)l = *(const uint4*)g;
#endif
}

// Stage one 16B chunk f of a [rows][32-ushort] tile.  Source slot XOR-swizzled
// with (row>>1)&3 (verified r7: conflicts 1.6e7 -> 3.7e6).  LDS dest stays
// lane-linear; read side applies the same involution.
#define SCH(gbase, stride, lds, f)                                               \
    gll16((gbase) + (size_t)((f) >> 2) * (stride)                                \
              + (((((f) & 3) ^ ((((f) >> 2) >> 1) & 3))) << 3),                  \
          (lds) + (f) * 8)

// Per-wave 64x64 output, 16x16x32 bf16 MFMA, K=32 per step, 32-ushort rows.
#define PREAMBLE(WM, WN)                                \
    const int t = threadIdx.x;                          \
    const int wid = t >> 6, l = t & 63;                 \
    const int wm = (WM), wn = (WN);                     \
    const int l15 = l & 15, lhi = l >> 4;               \
    const int swz8 = (lhi ^ ((l15 >> 1) & 3)) * 8;      \
    f32x4 acc[4][4];                                    \
    _Pragma("unroll")                                   \
    for (int a_ = 0; a_ < 4; ++a_)                      \
        _Pragma("unroll")                               \
        for (int b_ = 0; b_ < 4; ++b_)                  \
            acc[a_][b_] = (f32x4){0.f, 0.f, 0.f, 0.f};

#define MFMA_STEP(As, Bs)                                                        \
    {                                                                            \
        bf16x8 af_[4], bf_[4];                                                   \
        _Pragma("unroll")                                                        \
        for (int f_ = 0; f_ < 4; ++f_) {                                         \
            af_[f_] = *(const bf16x8*)((As) + (wm*64 + f_*16 + l15)*32 + swz8);  \
            bf_[f_] = *(const bf16x8*)((Bs) + (wn*64 + f_*16 + l15)*32 + swz8);  \
        }                                                                        \
        _Pragma("unroll")                                                        \
        for (int m_ = 0; m_ < 4; ++m_)                                           \
            _Pragma("unroll")                                                    \
            for (int n_ = 0; n_ < 4; ++n_)                                       \
                acc[m_][n_] = __builtin_amdgcn_mfma_f32_16x16x32_bf16(           \
                    af_[m_], bf_[n_], acc[m_][n_], 0, 0, 0);                     \
    }

// Double-buffered K-loop, __syncthreads-fenced (safe).  NIT even, >= 4.
#define DBUF(STG, NIT)                                                           \
    STG(0, A0, B0); __syncthreads();                                             \
    for (int itp = 0; itp < (NIT)/2 - 1; ++itp) {                                \
        STG(2*itp+1, A1, B1); MFMA_STEP(A0, B0); __syncthreads();                \
        STG(2*itp+2, A0, B0); MFMA_STEP(A1, B1); __syncthreads();                \
    }                                                                            \
    STG((NIT)-1, A1, B1); MFMA_STEP(A0, B0); __syncthreads();                    \
    MFMA_STEP(A1, B1); __syncthreads();

// ---------------------------------------------------------------------------
// x fp32 -> bf16, once.
// ---------------------------------------------------------------------------
__global__ __launch_bounds__(256) void convert_x(
    const float* __restrict__ x, ushort* __restrict__ xb)
{
    const size_t blk = (size_t)blockIdx.x * 4096;
    #pragma unroll
    for (int c = 0; c < 4; ++c) {
        const size_t s = blk + ((size_t)threadIdx.x + 256 * c) * 4;
        float4 a = *(const float4*)(x + s);
        ushort o[4] = {f2bf(a.x), f2bf(a.y), f2bf(a.z), f2bf(a.w)};
        *(uint2*)(xb + s) = *(uint2*)o;
    }
}

// ---------------------------------------------------------------------------
// Weights -> n-major bf16.
// ---------------------------------------------------------------------------
__global__ __launch_bounds__(256) void convert_w(
    const float* __restrict__ Wq, const float* __restrict__ Wk,
    const float* __restrict__ Wv, const float* __restrict__ Wo,
    ushort* __restrict__ WTqkv, ushort* __restrict__ WoT)
{
    const int id = blockIdx.x;      // 0..1023
    const int matn = id >> 8;
    const int n = id & 255;
    const int k = threadIdx.x;
    const float* W = (matn == 0) ? Wq : (matn == 1) ? Wk : (matn == 2) ? Wv : Wo;
    ushort v = f2bf(W[(size_t)k * E_ + n]);
    if (matn < 3) WTqkv[((size_t)matn * E_ + n) * E_ + k] = v;
    else          WoT[(size_t)n * E_ + k] = v;
}

// ---------------------------------------------------------------------------
// Fused QKV projection v2.  1536 blocks x 512 thr (8 waves 2x4).  Each block:
// one nt (128-col W panel held in REGISTERS, loaded once — scattered loads are
// acceptable exactly once) x 8 rc-tiles of 128 rows.  Per K-step only A is
// staged (1 gll16/thread, dbuf, __syncthreads-fenced).  Next tile's first
// A-stage issues before the epilogue so its latency hides under repack/stores.
// ---------------------------------------------------------------------------
__global__ __launch_bounds__(512) void qkv_mfma(
    const ushort* __restrict__ xb, const ushort* __restrict__ WT,
    const float* __restrict__ bq, const float* __restrict__ bk,
    const float* __restrict__ bv, const float* __restrict__ mask,
    ushort* __restrict__ qb, ushort* __restrict__ kb, ushort* __restrict__ vb)
{
    __shared__ __align__(16) ushort SR[128 * RP];   // repack region (34.8 KB)
    __shared__ __align__(16) ushort SA[2][4096];    // A dbuf (2 x 8 KB)
    const int id = ((blockIdx.x & 7) * 192) + (blockIdx.x >> 3);
    const int nt = id % 6;
    const int grp = id / 6;                 // 0..255
    const int t = threadIdx.x;
    const int wid = t >> 6, l = t & 63;
    const int wm = wid >> 2, wn = wid & 3;  // 2 x 4 waves; wave = 64m x 32n
    const int l15 = l & 15, lhi = l >> 4;
    const int swz8 = (lhi ^ ((l15 >> 1) & 3)) * 8;

    // --- B panel (weights) into registers, once. k-order identical to A's
    // canonical (row, k=lhi*8) pattern so intra-fragment permutation cancels.
    bf16x8 B[2][8];
    {
        const ushort* Bb = WT + (size_t)(nt * 128 + wn * 32 + l15) * E_ + lhi * 8;
        #pragma unroll
        for (int fb = 0; fb < 2; ++fb)
            #pragma unroll
            for (int ks = 0; ks < 8; ++ks)
                B[fb][ks] = *(const bf16x8*)(Bb + (size_t)fb * 16 * E_ + ks * 32);
    }

    const int proj = nt >> 1;
    const float* bias = (proj == 0) ? bq : (proj == 1) ? bk : bv;
    float bvv[2];
    #pragma unroll
    for (int fb = 0; fb < 2; ++fb)
        bvv[fb] = bias[(nt * 128 + wn * 32 + fb * 16 + l15) & 255];

#define QSTG(g, s, buf)                                                          \
    SCH(xb + (size_t)((grp * 8 + (g)) * 128) * E_ + (s) * 32, E_, buf, t)

#define QMFMA(buf)                                                               \
    {                                                                            \
        bf16x8 af_[4];                                                           \
        _Pragma("unroll")                                                        \
        for (int f_ = 0; f_ < 4; ++f_)                                           \
            af_[f_] = *(const bf16x8*)((buf) + (wm*64 + f_*16 + l15)*32 + swz8); \
        _Pragma("unroll")                                                        \
        for (int m_ = 0; m_ < 4; ++m_)                                           \
            _Pragma("unroll")                                                    \
            for (int n_ = 0; n_ < 2; ++n_)                                       \
                acc[m_][n_] = __builtin_amdgcn_mfma_f32_16x16x32_bf16(           \
                    af_[m_], B[n_][ks_], acc[m_][n_], 0, 0, 0);                  \
    }

    QSTG(0, 0, SA[0]);
    __syncthreads();

    for (int g = 0; g < 8; ++g) {
        f32x4 acc[4][2];
        #pragma unroll
        for (int m_ = 0; m_ < 4; ++m_)
            #pragma unroll
            for (int n_ = 0; n_ < 2; ++n_)
                acc[m_][n_] = (f32x4){0.f, 0.f, 0.f, 0.f};

        // 8 K-steps, dbuf; step s computes from SA[s&1], stages step s+1
        // (last step stages next tile's step 0 into SA[0] — no sync until
        // the epilogue's first barrier, which drains it under repack cover).
        #pragma unroll
        for (int s = 0; s < 8; ++s) {
            const int ks_ = s;
            if (s < 7)      QSTG(g, s + 1, SA[(s + 1) & 1]);
            else if (g < 7) QSTG(g + 1, 0, SA[0]);
            QMFMA(SA[s & 1]);
            if (s < 7) __syncthreads();
        }

        // --- epilogue: repack via SR, wide stores ---
        const int rc0 = (grp * 8 + g) * 128;
        #pragma unroll
        for (int fm = 0; fm < 4; ++fm)
            #pragma unroll
            for (int fb = 0; fb < 2; ++fb)
                #pragma unroll
                for (int rg = 0; rg < 4; ++rg) {
                    const int m = wm * 64 + fm * 16 + lhi * 4 + rg;
                    const int n = wn * 32 + fb * 16 + l15;
                    const ushort val = f2bf(acc[fm][fb][rg] + bvv[fb]);
                    if (proj < 2) SR[m * RP + n] = val;
                    else          SR[n * RP + m] = val;
                }
        __syncthreads();   // repack visible + next-tile A0 stage drained

        const int r = rc0 >> 9, c0 = rc0 & 511;
        if (proj < 2) {
            ushort* dst = (proj == 0) ? qb : kb;
            #pragma unroll
            for (int c = 0; c < 4; ++c) {
                const int idx = t + 512 * c;
                const int mrow = idx >> 4, ne = (idx & 15) * 8;
                uint4 w = *(const uint4*)(SR + mrow * RP + ne);
                if (proj == 0) {   // q: * 1/128 * (1-mask)
                    const float sk = 0.0078125f * (1.0f - mask[rc0 + mrow]);
                    ushort* ws = (ushort*)&w;
                    #pragma unroll
                    for (int jj = 0; jj < 8; ++jj) ws[jj] = f2bf(bf2f(ws[jj]) * sk);
                }
                const int e = (nt & 1) * 128 + ne, h = e >> 5, d = e & 31;
                *(uint4*)(dst + ((((size_t)h * R_ + r) * C_) + c0 + mrow) * D_ + d) = w;
            }
        } else {
            #pragma unroll
            for (int c = 0; c < 4; ++c) {
                const int idx = t + 512 * c;
                const int nrow = idx >> 4, m0 = (idx & 15) * 8;
                uint4 w = *(const uint4*)(SR + nrow * RP + m0);
                const int e = (nt & 1) * 128 + nrow, h = e >> 5, d = e & 31;
                *(uint4*)(vb + (((size_t)h * R_ + r) * D_ + d) * C_ + c0 + m0) = w;
            }
        }
        __syncthreads();   // SR free for next tile
    }
#undef QSTG
#undef QMFMA
}

// ---------------------------------------------------------------------------
// Attention logits.  128x128 tile, 256 threads, K split 8-way (1024 blocks).
// ---------------------------------------------------------------------------
__global__ __launch_bounds__(256) void logits_mfma(
    const ushort* __restrict__ qb, const ushort* __restrict__ kb,
    float* __restrict__ partial)
{
    __shared__ __align__(16) ushort S[16384];
    ushort* A0 = S;
    ushort* B0 = S + 4096;
    ushort* A1 = S + 8192;
    ushort* B1 = S + 12288;
    const int id = ((blockIdx.x & 7) * 128) + (blockIdx.x >> 3);
    const int sub = id & 15;
    const int j0 = (sub & 3) * 128;         // j fastest: 4 blocks share q panel
    const int i0 = (sub >> 2) * 128;
    const int hks = id >> 4;                // 0..63
    const int h = hks >> 3, ks = hks & 7;
    PREAMBLE(wid >> 1, wid & 1);

    const ushort* Ab = qb + (((size_t)h * R_ + ks * 64) * C_ + i0) * D_;
    const ushort* Bb = kb + (((size_t)h * R_ + ks * 64) * C_ + j0) * D_;

#define LSTG(i, Abuf, Bbuf) {                                   \
    const ushort* Ai = Ab + (size_t)(i) * (C_ * D_);            \
    const ushort* Bi = Bb + (size_t)(i) * (C_ * D_);            \
    SCH(Ai, D_, Abuf, t); SCH(Ai, D_, Abuf, t + 256);           \
    SCH(Bi, D_, Bbuf, t); SCH(Bi, D_, Bbuf, t + 256); }
    DBUF(LSTG, 64);

    float* dst = partial + ((size_t)ks * H_ + h) * C_ * C_;
    #pragma unroll
    for (int fm = 0; fm < 4; ++fm)
        #pragma unroll
        for (int rg = 0; rg < 4; ++rg) {
            const int i = i0 + wm * 64 + fm * 16 + lhi * 4 + rg;
            #pragma unroll
            for (int fn = 0; fn < 4; ++fn) {
                const int j = j0 + wn * 64 + fn * 16 + l15;
                dst[(size_t)i * C_ + j] = acc[fm][fn][rg];
            }
        }
}

// ---------------------------------------------------------------------------
// Sum 8 K-split partials + i-axis mask + softmax over j.
// ---------------------------------------------------------------------------
__global__ __launch_bounds__(256) void softmax_kernel(
    const float* __restrict__ partial, const float* __restrict__ mask,
    float* __restrict__ probs, ushort* __restrict__ Pb)
{
    const int hi = blockIdx.x;
    const int i = hi & 511;
    const int t = threadIdx.x;
    const size_t base = (size_t)hi * C_;
    const size_t stride = (size_t)H_ * C_ * C_;
    float v0 = 0.f, v1 = 0.f;
    #pragma unroll
    for (int ksp = 0; ksp < 8; ++ksp) {
        v0 += partial[ksp * stride + base + t];
        v1 += partial[ksp * stride + base + t + 256];
    }
    const float mi = mask[i];
    const float keep = 1.0f - mi;
    v0 = v0 * keep + mi * (-10000.0f);
    v1 = v1 * keep + mi * (-10000.0f);

    float m = fmaxf(v0, v1);
    #pragma unroll
    for (int off = 32; off > 0; off >>= 1) m = fmaxf(m, __shfl_xor(m, off));
    __shared__ float red[4];
    if ((t & 63) == 0) red[t >> 6] = m;
    __syncthreads();
    m = fmaxf(fmaxf(red[0], red[1]), fmaxf(red[2], red[3]));

    const float e0 = expf(v0 - m), e1 = expf(v1 - m);
    float s = e0 + e1;
    #pragma unroll
    for (int off = 32; off > 0; off >>= 1) s += __shfl_xor(s, off);
    __syncthreads();
    if ((t & 63) == 0) red[t >> 6] = s;
    __syncthreads();
    s = red[0] + red[1] + red[2] + red[3];

    const float inv = 1.0f / s;
    const float p0 = e0 * inv, p1 = e1 * inv;
    probs[base + t] = p0;
    probs[base + t + 256] = p1;
    Pb[base + t] = f2bf(p0);
    Pb[base + t + 256] = f2bf(p1);
}

// ---------------------------------------------------------------------------
// Context.  128x128 tile, 256 threads, 4096 blocks (one head per XCD).
// ---------------------------------------------------------------------------
__global__ __launch_bounds__(256) void context_mfma(
    const ushort* __restrict__ Pb, const ushort* __restrict__ vb,
    ushort* __restrict__ ctxb)
{
    __shared__ __align__(16) ushort S[128 * RP];
    ushort* A0 = S;
    ushort* B0 = S + 4096;
    ushort* A1 = S + 8192;
    ushort* B1 = S + 12288;
    const int id = ((blockIdx.x & 7) * 512) + (blockIdx.x >> 3);
    const int i0 = (id & 3) * 128;          // i fastest: 4 blocks share vb panel
    const int n0 = ((id >> 2) & 127) * 128;
    const int h = id >> 9;
    PREAMBLE(wid >> 1, wid & 1);

    const ushort* Ab = Pb + ((size_t)h * C_ + i0) * C_;
    const ushort* Bb = vb + ((size_t)h * R_ * D_ + n0) * C_;

#define CSTG(i, Abuf, Bbuf) {                                   \
    const ushort* Ai = Ab + (i) * 32;                           \
    const ushort* Bi = Bb + (i) * 32;                           \
    SCH(Ai, C_, Abuf, t); SCH(Ai, C_, Abuf, t + 256);           \
    SCH(Bi, C_, Bbuf, t); SCH(Bi, C_, Bbuf, t + 256); }
    DBUF(CSTG, 16);

    #pragma unroll
    for (int fm = 0; fm < 4; ++fm)
        #pragma unroll
        for (int fn = 0; fn < 4; ++fn)
            #pragma unroll
            for (int rg = 0; rg < 4; ++rg) {
                const int m = wm * 64 + fm * 16 + lhi * 4 + rg;
                const int n = wn * 64 + fn * 16 + l15;
                S[m * RP + n] = f2bf(acc[fm][fn][rg]);
            }
    __syncthreads();

    #pragma unroll
    for (int c = 0; c < 8; ++c) {
        const int idx = t + 256 * c;
        const int mrow = idx >> 4, nl = (idx & 15) * 8;
        uint4 w = *(const uint4*)(S + mrow * RP + nl);
        const int n = n0 + nl;
        const int rr = n >> 5, d = n & 31;
        const size_t rc = (size_t)rr * C_ + i0 + mrow;
        *(uint4*)(ctxb + rc * E_ + h * D_ + d) = w;
    }
}

// ---------------------------------------------------------------------------
// Output projection.  128x128 tile, 256 threads, 4096 blocks, fp32 out.
// ---------------------------------------------------------------------------
__global__ __launch_bounds__(256) void out_proj_mfma(
    const ushort* __restrict__ ctxb, const ushort* __restrict__ WoT,
    const float* __restrict__ bo, float* __restrict__ out)
{
    __shared__ __align__(16) ushort S[128 * RP];
    ushort* A0 = S;
    ushort* B0 = S + 4096;
    ushort* A1 = S + 8192;
    ushort* B1 = S + 12288;
    float* Sf = (float*)S;                  // 128 x 68 fp32 repack
    const int id = ((blockIdx.x & 7) * 512) + (blockIdx.x >> 3);
    const int n0 = (id & 1) * 128;
    const int rc0 = (id >> 1) * 128;
    PREAMBLE(wid >> 1, wid & 1);

    const ushort* Ab = ctxb + (size_t)rc0 * E_;
    const ushort* Bb = WoT + (size_t)n0 * E_;

#define OSTG(i, Abuf, Bbuf) {                                   \
    const ushort* Ai = Ab + (i) * 32;                           \
    const ushort* Bi = Bb + (i) * 32;                           \
    SCH(Ai, E_, Abuf, t); SCH(Ai, E_, Abuf, t + 256);           \
    SCH(Bi, E_, Bbuf, t); SCH(Bi, E_, Bbuf, t + 256); }
    DBUF(OSTG, 8);

    float bvv[4];
    #pragma unroll
    for (int fn = 0; fn < 4; ++fn)
        bvv[fn] = bo[n0 + wn * 64 + fn * 16 + l15];

    #pragma unroll
    for (int p = 0; p < 2; ++p) {
        #pragma unroll
        for (int fm = 0; fm < 4; ++fm)
            #pragma unroll
            for (int fh = 0; fh < 2; ++fh) {
                const int fn = 2 * p + fh;
                #pragma unroll
                for (int rg = 0; rg < 4; ++rg) {
                    const int m = wm * 64 + fm * 16 + lhi * 4 + rg;
                    const int s = wn * 32 + fh * 16 + l15;
                    Sf[m * 68 + s] = acc[fm][fn][rg] + bvv[fn];
                }
            }
        __syncthreads();
        #pragma unroll
        for (int c = 0; c < 8; ++c) {
            const int idx = t + 256 * c;
            const int row = idx >> 4, s0 = (idx & 15) * 4;
            float4 w = *(const float4*)(Sf + row * 68 + s0);
            const int ncol = n0 + (s0 >> 5) * 64 + (2 * p + ((s0 >> 4) & 1)) * 16 + (s0 & 15);
            *(float4*)(out + ((size_t)rc0 + row) * E_ + ncol) = w;
        }
        __syncthreads();
    }
}

// ---------------------------------------------------------------------------
extern "C" void kernel_launch(void* const* d_in, const int* in_sizes, int n_in,
                              void* d_out, int out_size, void* d_ws, size_t ws_size,
                              hipStream_t stream)
{
    const float* x    = (const float*)d_in[0];
    const float* mask = (const float*)d_in[1];
    const float* Wq   = (const float*)d_in[2];
    const float* bq   = (const float*)d_in[3];
    const float* Wk   = (const float*)d_in[4];
    const float* bk   = (const float*)d_in[5];
    const float* Wv   = (const float*)d_in[6];
    const float* bv   = (const float*)d_in[7];
    const float* Wo   = (const float*)d_in[8];
    const float* bo   = (const float*)d_in[9];

    float* out   = (float*)d_out;                       // [R,C,E] fp32
    float* probs = out + (size_t)RC_ * E_;              // [H,C,C] fp32

    char* ws = (char*)d_ws;
    ushort* qb      = (ushort*)(ws);                    // 128 MB  [h][r][c][d]
    ushort* kb      = (ushort*)(ws + 134217728ull);     // 128 MB  [h][r][c][d]
    ushort* vb      = (ushort*)(ws + 268435456ull);     // 128 MB  [h][r][d][c]
    ushort* ctxb    = (ushort*)(ws + 402653184ull);     // 128 MB  [rc][e]
    float*  partial = (float*)(ws + 536870912ull);      // 64 MB   [8][h][i][j]
    ushort* Pb      = (ushort*)(ws + 603979776ull);     // 4 MB    [h][i][j]
    ushort* WTqkv   = (ushort*)(ws + 608174080ull);     // 384 KB
    ushort* WoT     = (ushort*)(ws + 608567296ull);     // 128 KB
    ushort* xb      = (ushort*)(ws + 608700416ull);     // 128 MB  [rc][e]

    convert_x<<<16384, 256, 0, stream>>>(x, xb);
    convert_w<<<1024, 256, 0, stream>>>(Wq, Wk, Wv, Wo, WTqkv, WoT);
    qkv_mfma<<<1536, 512, 0, stream>>>(xb, WTqkv, bq, bk, bv, mask, qb, kb, vb);
    logits_mfma<<<1024, 256, 0, stream>>>(qb, kb, partial);
    softmax_kernel<<<4096, 256, 0, stream>>>(partial, mask, probs, Pb);
    context_mfma<<<4096, 256, 0, stream>>>(Pb, vb, ctxb);
    out_proj_mfma<<<4096, 256, 0, stream>>>(ctxb, WoT, bo, out);
}

// Round 11
// 661.645 us; speedup vs baseline: 1.2968x; 1.1080x over previous
//
#include <hip/hip_runtime.h>
#include <math.h>

#define R_ 512
#define C_ 512
#define E_ 256
#define H_ 8
#define D_ 32
#define RC_ (R_*C_)   // 262144
#define RP 136        // repack pitch (ushorts)

typedef __attribute__((ext_vector_type(8))) short bf16x8;
typedef __attribute__((ext_vector_type(4))) float f32x4;

__device__ __forceinline__ ushort f2bf(float f) {
    union { float f; unsigned u; } v; v.f = f;
    unsigned r = v.u + 0x7FFFu + ((v.u >> 16) & 1u);   // RNE
    return (ushort)(r >> 16);
}
__device__ __forceinline__ float bf2f(ushort u) {
    union { unsigned u; float f; } v; v.u = ((unsigned)u) << 16;
    return v.f;
}

// 16B global->LDS direct copy (lane-linear dest), fallback = reg staging.
__device__ __forceinline__ void gll16(const ushort* g, ushort* l) {
#if __has_builtin(__builtin_amdgcn_global_load_lds)
    __builtin_amdgcn_global_load_lds(
        (const __attribute__((address_space(1))) unsigned*)(unsigned long long)g,
        (__attribute__((address_space(3))) unsigned*)(unsigned)(unsigned long long)l,
        16, 0, 0);
#else
    *(uint4*)l = *(const uint4*)g;
#endif
}

// Stage one 16B chunk f of a [rows][32-ushort] tile.  Source slot XOR-swizzled
// with (row>>1)&3 (verified r7: conflicts 1.6e7 -> 3.7e6).  LDS dest stays
// lane-linear; read side applies the same involution.
#define SCH(gbase, stride, lds, f)                                               \
    gll16((gbase) + (size_t)((f) >> 2) * (stride)                                \
              + (((((f) & 3) ^ ((((f) >> 2) >> 1) & 3))) << 3),                  \
          (lds) + (f) * 8)

// --- T4 counted-vmcnt sync, with the BOTH fences rule #18 requires.
// r5/r10 raced because register-only MFMAs sink past asm "memory" barriers,
// dragging lgkm waits with them -> ds_reads still in flight at the reuse
// barrier.  Fix: explicit lgkmcnt(0) before the reuse barrier + sched_barrier(0)
// at every sync point so NOTHING (incl. MFMA) crosses.
#define SCHED0   __builtin_amdgcn_sched_barrier(0)
#define ABAR     __builtin_amdgcn_s_barrier()
#define VMCNT(N) asm volatile("s_waitcnt vmcnt(" #N ")" ::: "memory")
#define LGKM0    asm volatile("s_waitcnt lgkmcnt(0)" ::: "memory")
// loads-landed barrier: my N newest loads may stay in flight
#define SYNC_IN(N) do { VMCNT(N); SCHED0; ABAR; SCHED0; } while (0)
// reads-complete barrier: all my ds_reads retired before anyone overwrites
#define SYNC_OUT   do { LGKM0; SCHED0; ABAR; SCHED0; } while (0)

// Per-wave 64x64 output, 16x16x32 bf16 MFMA, K=32 per step, 32-ushort rows.
#define PREAMBLE(WM, WN)                                \
    const int t = threadIdx.x;                          \
    const int wid = t >> 6, l = t & 63;                 \
    const int wm = (WM), wn = (WN);                     \
    const int l15 = l & 15, lhi = l >> 4;               \
    const int swz8 = (lhi ^ ((l15 >> 1) & 3)) * 8;      \
    f32x4 acc[4][4];                                    \
    _Pragma("unroll")                                   \
    for (int a_ = 0; a_ < 4; ++a_)                      \
        _Pragma("unroll")                               \
        for (int b_ = 0; b_ < 4; ++b_)                  \
            acc[a_][b_] = (f32x4){0.f, 0.f, 0.f, 0.f};

#define MFMA_STEP(As, Bs)                                                        \
    {                                                                            \
        bf16x8 af_[4], bf_[4];                                                   \
        _Pragma("unroll")                                                        \
        for (int f_ = 0; f_ < 4; ++f_) {                                         \
            af_[f_] = *(const bf16x8*)((As) + (wm*64 + f_*16 + l15)*32 + swz8);  \
            bf_[f_] = *(const bf16x8*)((Bs) + (wn*64 + f_*16 + l15)*32 + swz8);  \
        }                                                                        \
        _Pragma("unroll")                                                        \
        for (int m_ = 0; m_ < 4; ++m_)                                           \
            _Pragma("unroll")                                                    \
            for (int n_ = 0; n_ < 4; ++n_)                                       \
                acc[m_][n_] = __builtin_amdgcn_mfma_f32_16x16x32_bf16(           \
                    af_[m_], bf_[n_], acc[m_][n_], 0, 0, 0);                     \
    }

// Counted-vmcnt double-buffered K-loop (T3+T4).  Each STG = 4 global_load_lds
// per thread.  SYNC_IN(4): this step's 4 loads stay in flight, the previous
// step's (into the buffer about to be read) are landed; the barrier publishes
// every wave's LDS writes.  SYNC_OUT: all ds_reads retired before reuse.
// In-loop vmcnt never 0.  NIT even, >= 4.
#define DBUFC(STG, NIT)                                                          \
    STG(0, A0, B0);                                                              \
    for (int itp = 0; itp < (NIT)/2; ++itp) {                                    \
        STG(2*itp+1, A1, B1);                                                    \
        SYNC_IN(4);                                                              \
        MFMA_STEP(A0, B0);                                                       \
        SYNC_OUT;                                                                \
        if (itp < (NIT)/2 - 1) { STG(2*itp+2, A0, B0); SYNC_IN(4); }             \
        else                   { SYNC_IN(0); }                                   \
        MFMA_STEP(A1, B1);                                                       \
        SYNC_OUT;                                                                \
    }

// ---------------------------------------------------------------------------
// x fp32 -> bf16, once.
// ---------------------------------------------------------------------------
__global__ __launch_bounds__(256) void convert_x(
    const float* __restrict__ x, ushort* __restrict__ xb)
{
    const size_t blk = (size_t)blockIdx.x * 4096;
    #pragma unroll
    for (int c = 0; c < 4; ++c) {
        const size_t s = blk + ((size_t)threadIdx.x + 256 * c) * 4;
        float4 a = *(const float4*)(x + s);
        ushort o[4] = {f2bf(a.x), f2bf(a.y), f2bf(a.z), f2bf(a.w)};
        *(uint2*)(xb + s) = *(uint2*)o;
    }
}

// ---------------------------------------------------------------------------
// Weights -> n-major bf16.
// ---------------------------------------------------------------------------
__global__ __launch_bounds__(256) void convert_w(
    const float* __restrict__ Wq, const float* __restrict__ Wk,
    const float* __restrict__ Wv, const float* __restrict__ Wo,
    ushort* __restrict__ WTqkv, ushort* __restrict__ WoT)
{
    const int id = blockIdx.x;      // 0..1023
    const int matn = id >> 8;
    const int n = id & 255;
    const int k = threadIdx.x;
    const float* W = (matn == 0) ? Wq : (matn == 1) ? Wk : (matn == 2) ? Wv : Wo;
    ushort v = f2bf(W[(size_t)k * E_ + n]);
    if (matn < 3) WTqkv[((size_t)matn * E_ + n) * E_ + k] = v;
    else          WoT[(size_t)n * E_ + k] = v;
}

// ---------------------------------------------------------------------------
// Fused QKV projection (r6 geometry + fenced T4 sync).  12288 blocks x 256
// thr (4 waves 2x2), XCD-chunked, nt fastest.  Epilogue repack -> uint4
// stores; v transposed in LDS.
// ---------------------------------------------------------------------------
__global__ __launch_bounds__(256) void qkv_mfma(
    const ushort* __restrict__ xb, const ushort* __restrict__ WT,
    const float* __restrict__ bq, const float* __restrict__ bk,
    const float* __restrict__ bv, const float* __restrict__ mask,
    ushort* __restrict__ qb, ushort* __restrict__ kb, ushort* __restrict__ vb)
{
    __shared__ __align__(16) ushort S[128 * RP];   // staging dbuf + repack alias
    ushort* A0 = S;
    ushort* B0 = S + 4096;
    ushort* A1 = S + 8192;
    ushort* B1 = S + 12288;
    const int id = ((blockIdx.x & 7) * 1536) + (blockIdx.x >> 3);
    const int nt = id % 6;
    const int rc0 = (id / 6) * 128;
    PREAMBLE(wid >> 1, wid & 1);

    const ushort* Ab = xb + (size_t)rc0 * E_;
    const ushort* Bb = WT + (size_t)nt * 128 * E_;

#define QSTG(i, Abuf, Bbuf) {                                   \
    const ushort* Ai = Ab + (i) * 32;                           \
    const ushort* Bi = Bb + (i) * 32;                           \
    SCH(Ai, E_, Abuf, t); SCH(Ai, E_, Abuf, t + 256);           \
    SCH(Bi, E_, Bbuf, t); SCH(Bi, E_, Bbuf, t + 256); }
    DBUFC(QSTG, 8);

    const int proj = nt >> 1;
    const float* bias = (proj == 0) ? bq : (proj == 1) ? bk : bv;
    float bvv[4];
    #pragma unroll
    for (int fn = 0; fn < 4; ++fn)
        bvv[fn] = bias[(nt * 128 + wn * 64 + fn * 16 + l15) & 255];

    // repack: q/k as [c][e], v as [e][c]
    #pragma unroll
    for (int fm = 0; fm < 4; ++fm)
        #pragma unroll
        for (int fn = 0; fn < 4; ++fn)
            #pragma unroll
            for (int rg = 0; rg < 4; ++rg) {
                const int m = wm * 64 + fm * 16 + lhi * 4 + rg;
                const int n = wn * 64 + fn * 16 + l15;
                const ushort val = f2bf(acc[fm][fn][rg] + bvv[fn]);
                if (proj < 2) S[m * RP + n] = val;
                else          S[n * RP + m] = val;
            }
    __syncthreads();

    const int r = rc0 >> 9, c0 = rc0 & 511;
    if (proj < 2) {
        ushort* dst = (proj == 0) ? qb : kb;
        #pragma unroll
        for (int c = 0; c < 8; ++c) {
            const int idx = t + 256 * c;
            const int mrow = idx >> 4, ne = (idx & 15) * 8;
            uint4 w = *(const uint4*)(S + mrow * RP + ne);
            if (proj == 0) {   // q: * 1/128 * (1-mask)
                const float sk = 0.0078125f * (1.0f - mask[rc0 + mrow]);
                ushort* ws = (ushort*)&w;
                #pragma unroll
                for (int jj = 0; jj < 8; ++jj) ws[jj] = f2bf(bf2f(ws[jj]) * sk);
            }
            const int e = (nt & 1) * 128 + ne, h = e >> 5, d = e & 31;
            *(uint4*)(dst + ((((size_t)h * R_ + r) * C_) + c0 + mrow) * D_ + d) = w;
        }
    } else {
        #pragma unroll
        for (int c = 0; c < 8; ++c) {
            const int idx = t + 256 * c;
            const int nrow = idx >> 4, m0 = (idx & 15) * 8;
            uint4 w = *(const uint4*)(S + nrow * RP + m0);
            const int e = (nt & 1) * 128 + nrow, h = e >> 5, d = e & 31;
            *(uint4*)(vb + (((size_t)h * R_ + r) * D_ + d) * C_ + c0 + m0) = w;
        }
    }
}

// ---------------------------------------------------------------------------
// Attention logits.  128x128 tile, 256 threads, K split 8-way (1024 blocks).
// ---------------------------------------------------------------------------
__global__ __launch_bounds__(256) void logits_mfma(
    const ushort* __restrict__ qb, const ushort* __restrict__ kb,
    float* __restrict__ partial)
{
    __shared__ __align__(16) ushort S[16384];
    ushort* A0 = S;
    ushort* B0 = S + 4096;
    ushort* A1 = S + 8192;
    ushort* B1 = S + 12288;
    const int id = ((blockIdx.x & 7) * 128) + (blockIdx.x >> 3);
    const int sub = id & 15;
    const int j0 = (sub & 3) * 128;         // j fastest: 4 blocks share q panel
    const int i0 = (sub >> 2) * 128;
    const int hks = id >> 4;                // 0..63
    const int h = hks >> 3, ks = hks & 7;
    PREAMBLE(wid >> 1, wid & 1);

    const ushort* Ab = qb + (((size_t)h * R_ + ks * 64) * C_ + i0) * D_;
    const ushort* Bb = kb + (((size_t)h * R_ + ks * 64) * C_ + j0) * D_;

#define LSTG(i, Abuf, Bbuf) {                                   \
    const ushort* Ai = Ab + (size_t)(i) * (C_ * D_);            \
    const ushort* Bi = Bb + (size_t)(i) * (C_ * D_);            \
    SCH(Ai, D_, Abuf, t); SCH(Ai, D_, Abuf, t + 256);           \
    SCH(Bi, D_, Bbuf, t); SCH(Bi, D_, Bbuf, t + 256); }
    DBUFC(LSTG, 64);

    float* dst = partial + ((size_t)ks * H_ + h) * C_ * C_;
    #pragma unroll
    for (int fm = 0; fm < 4; ++fm)
        #pragma unroll
        for (int rg = 0; rg < 4; ++rg) {
            const int i = i0 + wm * 64 + fm * 16 + lhi * 4 + rg;
            #pragma unroll
            for (int fn = 0; fn < 4; ++fn) {
                const int j = j0 + wn * 64 + fn * 16 + l15;
                dst[(size_t)i * C_ + j] = acc[fm][fn][rg];
            }
        }
}

// ---------------------------------------------------------------------------
// Sum 8 K-split partials + i-axis mask + softmax over j.
// ---------------------------------------------------------------------------
__global__ __launch_bounds__(256) void softmax_kernel(
    const float* __restrict__ partial, const float* __restrict__ mask,
    float* __restrict__ probs, ushort* __restrict__ Pb)
{
    const int hi = blockIdx.x;
    const int i = hi & 511;
    const int t = threadIdx.x;
    const size_t base = (size_t)hi * C_;
    const size_t stride = (size_t)H_ * C_ * C_;
    float v0 = 0.f, v1 = 0.f;
    #pragma unroll
    for (int ksp = 0; ksp < 8; ++ksp) {
        v0 += partial[ksp * stride + base + t];
        v1 += partial[ksp * stride + base + t + 256];
    }
    const float mi = mask[i];
    const float keep = 1.0f - mi;
    v0 = v0 * keep + mi * (-10000.0f);
    v1 = v1 * keep + mi * (-10000.0f);

    float m = fmaxf(v0, v1);
    #pragma unroll
    for (int off = 32; off > 0; off >>= 1) m = fmaxf(m, __shfl_xor(m, off));
    __shared__ float red[4];
    if ((t & 63) == 0) red[t >> 6] = m;
    __syncthreads();
    m = fmaxf(fmaxf(red[0], red[1]), fmaxf(red[2], red[3]));

    const float e0 = expf(v0 - m), e1 = expf(v1 - m);
    float s = e0 + e1;
    #pragma unroll
    for (int off = 32; off > 0; off >>= 1) s += __shfl_xor(s, off);
    __syncthreads();
    if ((t & 63) == 0) red[t >> 6] = s;
    __syncthreads();
    s = red[0] + red[1] + red[2] + red[3];

    const float inv = 1.0f / s;
    const float p0 = e0 * inv, p1 = e1 * inv;
    probs[base + t] = p0;
    probs[base + t + 256] = p1;
    Pb[base + t] = f2bf(p0);
    Pb[base + t + 256] = f2bf(p1);
}

// ---------------------------------------------------------------------------
// Context.  128x128 tile, 256 threads, 4096 blocks (one head per XCD).
// ---------------------------------------------------------------------------
__global__ __launch_bounds__(256) void context_mfma(
    const ushort* __restrict__ Pb, const ushort* __restrict__ vb,
    ushort* __restrict__ ctxb)
{
    __shared__ __align__(16) ushort S[128 * RP];
    ushort* A0 = S;
    ushort* B0 = S + 4096;
    ushort* A1 = S + 8192;
    ushort* B1 = S + 12288;
    const int id = ((blockIdx.x & 7) * 512) + (blockIdx.x >> 3);
    const int i0 = (id & 3) * 128;          // i fastest: 4 blocks share vb panel
    const int n0 = ((id >> 2) & 127) * 128;
    const int h = id >> 9;
    PREAMBLE(wid >> 1, wid & 1);

    const ushort* Ab = Pb + ((size_t)h * C_ + i0) * C_;
    const ushort* Bb = vb + ((size_t)h * R_ * D_ + n0) * C_;

#define CSTG(i, Abuf, Bbuf) {                                   \
    const ushort* Ai = Ab + (i) * 32;                           \
    const ushort* Bi = Bb + (i) * 32;                           \
    SCH(Ai, C_, Abuf, t); SCH(Ai, C_, Abuf, t + 256);           \
    SCH(Bi, C_, Bbuf, t); SCH(Bi, C_, Bbuf, t + 256); }
    DBUFC(CSTG, 16);

    #pragma unroll
    for (int fm = 0; fm < 4; ++fm)
        #pragma unroll
        for (int fn = 0; fn < 4; ++fn)
            #pragma unroll
            for (int rg = 0; rg < 4; ++rg) {
                const int m = wm * 64 + fm * 16 + lhi * 4 + rg;
                const int n = wn * 64 + fn * 16 + l15;
                S[m * RP + n] = f2bf(acc[fm][fn][rg]);
            }
    __syncthreads();

    #pragma unroll
    for (int c = 0; c < 8; ++c) {
        const int idx = t + 256 * c;
        const int mrow = idx >> 4, nl = (idx & 15) * 8;
        uint4 w = *(const uint4*)(S + mrow * RP + nl);
        const int n = n0 + nl;
        const int rr = n >> 5, d = n & 31;
        const size_t rc = (size_t)rr * C_ + i0 + mrow;
        *(uint4*)(ctxb + rc * E_ + h * D_ + d) = w;
    }
}

// ---------------------------------------------------------------------------
// Output projection.  128x128 tile, 256 threads, 4096 blocks, fp32 out.
// ---------------------------------------------------------------------------
__global__ __launch_bounds__(256) void out_proj_mfma(
    const ushort* __restrict__ ctxb, const ushort* __restrict__ WoT,
    const float* __restrict__ bo, float* __restrict__ out)
{
    __shared__ __align__(16) ushort S[128 * RP];
    ushort* A0 = S;
    ushort* B0 = S + 4096;
    ushort* A1 = S + 8192;
    ushort* B1 = S + 12288;
    float* Sf = (float*)S;                  // 128 x 68 fp32 repack
    const int id = ((blockIdx.x & 7) * 512) + (blockIdx.x >> 3);
    const int n0 = (id & 1) * 128;
    const int rc0 = (id >> 1) * 128;
    PREAMBLE(wid >> 1, wid & 1);

    const ushort* Ab = ctxb + (size_t)rc0 * E_;
    const ushort* Bb = WoT + (size_t)n0 * E_;

#define OSTG(i, Abuf, Bbuf) {                                   \
    const ushort* Ai = Ab + (i) * 32;                           \
    const ushort* Bi = Bb + (i) * 32;                           \
    SCH(Ai, E_, Abuf, t); SCH(Ai, E_, Abuf, t + 256);           \
    SCH(Bi, E_, Bbuf, t); SCH(Bi, E_, Bbuf, t + 256); }
    DBUFC(OSTG, 8);

    float bvv[4];
    #pragma unroll
    for (int fn = 0; fn < 4; ++fn)
        bvv[fn] = bo[n0 + wn * 64 + fn * 16 + l15];

    #pragma unroll
    for (int p = 0; p < 2; ++p) {
        #pragma unroll
        for (int fm = 0; fm < 4; ++fm)
            #pragma unroll
            for (int fh = 0; fh < 2; ++fh) {
                const int fn = 2 * p + fh;
                #pragma unroll
                for (int rg = 0; rg < 4; ++rg) {
                    const int m = wm * 64 + fm * 16 + lhi * 4 + rg;
                    const int s = wn * 32 + fh * 16 + l15;
                    Sf[m * 68 + s] = acc[fm][fn][rg] + bvv[fn];
                }
            }
        __syncthreads();
        #pragma unroll
        for (int c = 0; c < 8; ++c) {
            const int idx = t + 256 * c;
            const int row = idx >> 4, s0 = (idx & 15) * 4;
            float4 w = *(const float4*)(Sf + row * 68 + s0);
            const int ncol = n0 + (s0 >> 5) * 64 + (2 * p + ((s0 >> 4) & 1)) * 16 + (s0 & 15);
            *(float4*)(out + ((size_t)rc0 + row) * E_ + ncol) = w;
        }
        __syncthreads();
    }
}

// ---------------------------------------------------------------------------
extern "C" void kernel_launch(void* const* d_in, const int* in_sizes, int n_in,
                              void* d_out, int out_size, void* d_ws, size_t ws_size,
                              hipStream_t stream)
{
    const float* x    = (const float*)d_in[0];
    const float* mask = (const float*)d_in[1];
    const float* Wq   = (const float*)d_in[2];
    const float* bq   = (const float*)d_in[3];
    const float* Wk   = (const float*)d_in[4];
    const float* bk   = (const float*)d_in[5];
    const float* Wv   = (const float*)d_in[6];
    const float* bv   = (const float*)d_in[7];
    const float* Wo   = (const float*)d_in[8];
    const float* bo   = (const float*)d_in[9];

    float* out   = (float*)d_out;                       // [R,C,E] fp32
    float* probs = out + (size_t)RC_ * E_;              // [H,C,C] fp32

    char* ws = (char*)d_ws;
    ushort* qb      = (ushort*)(ws);                    // 128 MB  [h][r][c][d]
    ushort* kb      = (ushort*)(ws + 134217728ull);     // 128 MB  [h][r][c][d]
    ushort* vb      = (ushort*)(ws + 268435456ull);     // 128 MB  [h][r][d][c]
    ushort* ctxb    = (ushort*)(ws + 402653184ull);     // 128 MB  [rc][e]
    float*  partial = (float*)(ws + 536870912ull);      // 64 MB   [8][h][i][j]
    ushort* Pb      = (ushort*)(ws + 603979776ull);     // 4 MB    [h][i][j]
    ushort* WTqkv   = (ushort*)(ws + 608174080ull);     // 384 KB
    ushort* WoT     = (ushort*)(ws + 608567296ull);     // 128 KB
    ushort* xb      = (ushort*)(ws + 608700416ull);     // 128 MB  [rc][e]

    convert_x<<<16384, 256, 0, stream>>>(x, xb);
    convert_w<<<1024, 256, 0, stream>>>(Wq, Wk, Wv, Wo, WTqkv, WoT);
    qkv_mfma<<<12288, 256, 0, stream>>>(xb, WTqkv, bq, bk, bv, mask, qb, kb, vb);
    logits_mfma<<<1024, 256, 0, stream>>>(qb, kb, partial);
    softmax_kernel<<<4096, 256, 0, stream>>>(partial, mask, probs, Pb);
    context_mfma<<<4096, 256, 0, stream>>>(Pb, vb, ctxb);
    out_proj_mfma<<<4096, 256, 0, stream>>>(ctxb, WoT, bo, out);
}

// Round 12
// 626.868 us; speedup vs baseline: 1.3687x; 1.0555x over previous
//
#include <hip/hip_runtime.h>
#include <math.h>

#define R_ 512
#define C_ 512
#define E_ 256
#define H_ 8
#define D_ 32
#define RC_ (R_*C_)   // 262144
#define RP 136        // repack pitch (ushorts)

typedef __attribute__((ext_vector_type(8))) short bf16x8;
typedef __attribute__((ext_vector_type(4))) float f32x4;

__device__ __forceinline__ ushort f2bf(float f) {
    union { float f; unsigned u; } v; v.f = f;
    unsigned r = v.u + 0x7FFFu + ((v.u >> 16) & 1u);   // RNE
    return (ushort)(r >> 16);
}
__device__ __forceinline__ float bf2f(ushort u) {
    union { unsigned u; float f; } v; v.u = ((unsigned)u) << 16;
    return v.f;
}

// 16B global->LDS direct copy (lane-linear dest), fallback = reg staging.
__device__ __forceinline__ void gll16(const ushort* g, ushort* l) {
#if __has_builtin(__builtin_amdgcn_global_load_lds)
    __builtin_amdgcn_global_load_lds(
        (const __attribute__((address_space(1))) unsigned*)(unsigned long long)g,
        (__attribute__((address_space(3))) unsigned*)(unsigned)(unsigned long long)l,
        16, 0, 0);
#else
    *(uint4*)l = *(const uint4*)g;
#endif
}

// Stage one 16B chunk f of a [rows][32-ushort] tile.  Source slot XOR-swizzled
// with (row>>1)&3 (verified r7: conflicts 1.6e7 -> 3.7e6).  LDS dest stays
// lane-linear; read side applies the same involution.
#define SCH(gbase, stride, lds, f)                                               \
    gll16((gbase) + (size_t)((f) >> 2) * (stride)                                \
              + (((((f) & 3) ^ ((((f) >> 2) >> 1) & 3))) << 3),                  \
          (lds) + (f) * 8)

// --- Fenced sync primitives (validated r11: rule #18 double-fence).
#define SCHED0   __builtin_amdgcn_sched_barrier(0)
#define ABAR     __builtin_amdgcn_s_barrier()
#define VMCNT(N) asm volatile("s_waitcnt vmcnt(" #N ")" ::: "memory")

// Per-wave 64x64 output, 16x16x32 bf16 MFMA, K=32 per step, 32-ushort rows.
#define PREAMBLE(WM, WN)                                \
    const int t = threadIdx.x;                          \
    const int wid = t >> 6, l = t & 63;                 \
    const int wm = (WM), wn = (WN);                     \
    const int l15 = l & 15, lhi = l >> 4;               \
    const int swz8 = (lhi ^ ((l15 >> 1) & 3)) * 8;      \
    f32x4 acc[4][4];                                    \
    _Pragma("unroll")                                   \
    for (int a_ = 0; a_ < 4; ++a_)                      \
        _Pragma("unroll")                               \
        for (int b_ = 0; b_ < 4; ++b_)                  \
            acc[a_][b_] = (f32x4){0.f, 0.f, 0.f, 0.f};

#define MFMA_STEP(As, Bs)                                                        \
    {                                                                            \
        bf16x8 af_[4], bf_[4];                                                   \
        _Pragma("unroll")                                                        \
        for (int f_ = 0; f_ < 4; ++f_) {                                         \
            af_[f_] = *(const bf16x8*)((As) + (wm*64 + f_*16 + l15)*32 + swz8);  \
            bf_[f_] = *(const bf16x8*)((Bs) + (wn*64 + f_*16 + l15)*32 + swz8);  \
        }                                                                        \
        _Pragma("unroll")                                                        \
        for (int m_ = 0; m_ < 4; ++m_)                                           \
            _Pragma("unroll")                                                    \
            for (int n_ = 0; n_ < 4; ++n_)                                       \
                acc[m_][n_] = __builtin_amdgcn_mfma_f32_16x16x32_bf16(           \
                    af_[m_], bf_[n_], acc[m_][n_], 0, 0, 0);                     \
    }

// Triple-buffered K-loop, ONE fenced barrier per step, prefetch distance 2.
// Step s: VMCNT(4) [own STG(s) landed; STG(s+1) stays in flight] -> barrier
// [publishes all waves' buf(s) writes; also proves all step s-1 ds_reads
// retired, since MFMA issue implies operand ds_reads retired and MFMAs are
// SCHED0-fenced before the barrier] -> STG(s+2) into buf[(s-1)%3] [safe WAR]
// -> MFMA(s).  In-loop vmcnt never 0 except the final step's drain.
// Requires A0..A2/B0..B2; each STG = 4 gll16/thread.  NIT >= 3.
#define DBUFT(STG, NIT)                                                          \
    STG(0, A0, B0); STG(1, A1, B1);                                              \
    _Pragma("unroll")                                                            \
    for (int s = 0; s < (NIT); ++s) {                                            \
        if (s < (NIT) - 1) { VMCNT(4); } else { VMCNT(0); }                      \
        SCHED0; ABAR; SCHED0;                                                    \
        if (s + 2 < (NIT)) {                                                     \
            if (((s + 2) % 3) == 0)      { STG(s + 2, A0, B0); }                 \
            else if (((s + 2) % 3) == 1) { STG(s + 2, A1, B1); }                 \
            else                         { STG(s + 2, A2, B2); }                 \
        }                                                                        \
        if ((s % 3) == 0)      { MFMA_STEP(A0, B0); }                            \
        else if ((s % 3) == 1) { MFMA_STEP(A1, B1); }                            \
        else                   { MFMA_STEP(A2, B2); }                            \
    }

#define BUFS3 ushort* A0 = S;          ushort* B0 = S + 4096;                    \
              ushort* A1 = S + 8192;   ushort* B1 = S + 12288;                   \
              ushort* A2 = S + 16384;  ushort* B2 = S + 20480;

// ---------------------------------------------------------------------------
// x fp32 -> bf16, once.
// ---------------------------------------------------------------------------
__global__ __launch_bounds__(256) void convert_x(
    const float* __restrict__ x, ushort* __restrict__ xb)
{
    const size_t blk = (size_t)blockIdx.x * 4096;
    #pragma unroll
    for (int c = 0; c < 4; ++c) {
        const size_t s = blk + ((size_t)threadIdx.x + 256 * c) * 4;
        float4 a = *(const float4*)(x + s);
        ushort o[4] = {f2bf(a.x), f2bf(a.y), f2bf(a.z), f2bf(a.w)};
        *(uint2*)(xb + s) = *(uint2*)o;
    }
}

// ---------------------------------------------------------------------------
// Weights -> n-major bf16.
// ---------------------------------------------------------------------------
__global__ __launch_bounds__(256) void convert_w(
    const float* __restrict__ Wq, const float* __restrict__ Wk,
    const float* __restrict__ Wv, const float* __restrict__ Wo,
    ushort* __restrict__ WTqkv, ushort* __restrict__ WoT)
{
    const int id = blockIdx.x;      // 0..1023
    const int matn = id >> 8;
    const int n = id & 255;
    const int k = threadIdx.x;
    const float* W = (matn == 0) ? Wq : (matn == 1) ? Wk : (matn == 2) ? Wv : Wo;
    ushort v = f2bf(W[(size_t)k * E_ + n]);
    if (matn < 3) WTqkv[((size_t)matn * E_ + n) * E_ + k] = v;
    else          WoT[(size_t)n * E_ + k] = v;
}

// ---------------------------------------------------------------------------
// Fused QKV projection (r6 geometry + triple-buffer T3/T4 schedule).
// 12288 blocks x 256 thr (4 waves 2x2), XCD-chunked, nt fastest.  Epilogue
// repack -> uint4 stores; v transposed in LDS.
// ---------------------------------------------------------------------------
__global__ __launch_bounds__(256) void qkv_mfma(
    const ushort* __restrict__ xb, const ushort* __restrict__ WT,
    const float* __restrict__ bq, const float* __restrict__ bk,
    const float* __restrict__ bv, const float* __restrict__ mask,
    ushort* __restrict__ qb, ushort* __restrict__ kb, ushort* __restrict__ vb)
{
    __shared__ __align__(16) ushort S[24576];   // 48KB staging; repack aliases
    BUFS3;
    const int id = ((blockIdx.x & 7) * 1536) + (blockIdx.x >> 3);
    const int nt = id % 6;
    const int rc0 = (id / 6) * 128;
    PREAMBLE(wid >> 1, wid & 1);

    const ushort* Ab = xb + (size_t)rc0 * E_;
    const ushort* Bb = WT + (size_t)nt * 128 * E_;

#define QSTG(i, Abuf, Bbuf) {                                   \
    const ushort* Ai = Ab + (i) * 32;                           \
    const ushort* Bi = Bb + (i) * 32;                           \
    SCH(Ai, E_, Abuf, t); SCH(Ai, E_, Abuf, t + 256);           \
    SCH(Bi, E_, Bbuf, t); SCH(Bi, E_, Bbuf, t + 256); }
    DBUFT(QSTG, 8);
    __syncthreads();   // all waves done reading staging before repack alias

    const int proj = nt >> 1;
    const float* bias = (proj == 0) ? bq : (proj == 1) ? bk : bv;
    float bvv[4];
    #pragma unroll
    for (int fn = 0; fn < 4; ++fn)
        bvv[fn] = bias[(nt * 128 + wn * 64 + fn * 16 + l15) & 255];

    // repack: q/k as [c][e], v as [e][c]
    #pragma unroll
    for (int fm = 0; fm < 4; ++fm)
        #pragma unroll
        for (int fn = 0; fn < 4; ++fn)
            #pragma unroll
            for (int rg = 0; rg < 4; ++rg) {
                const int m = wm * 64 + fm * 16 + lhi * 4 + rg;
                const int n = wn * 64 + fn * 16 + l15;
                const ushort val = f2bf(acc[fm][fn][rg] + bvv[fn]);
                if (proj < 2) S[m * RP + n] = val;
                else          S[n * RP + m] = val;
            }
    __syncthreads();

    const int r = rc0 >> 9, c0 = rc0 & 511;
    if (proj < 2) {
        ushort* dst = (proj == 0) ? qb : kb;
        #pragma unroll
        for (int c = 0; c < 8; ++c) {
            const int idx = t + 256 * c;
            const int mrow = idx >> 4, ne = (idx & 15) * 8;
            uint4 w = *(const uint4*)(S + mrow * RP + ne);
            if (proj == 0) {   // q: * 1/128 * (1-mask)
                const float sk = 0.0078125f * (1.0f - mask[rc0 + mrow]);
                ushort* ws = (ushort*)&w;
                #pragma unroll
                for (int jj = 0; jj < 8; ++jj) ws[jj] = f2bf(bf2f(ws[jj]) * sk);
            }
            const int e = (nt & 1) * 128 + ne, h = e >> 5, d = e & 31;
            *(uint4*)(dst + ((((size_t)h * R_ + r) * C_) + c0 + mrow) * D_ + d) = w;
        }
    } else {
        #pragma unroll
        for (int c = 0; c < 8; ++c) {
            const int idx = t + 256 * c;
            const int nrow = idx >> 4, m0 = (idx & 15) * 8;
            uint4 w = *(const uint4*)(S + nrow * RP + m0);
            const int e = (nt & 1) * 128 + nrow, h = e >> 5, d = e & 31;
            *(uint4*)(vb + (((size_t)h * R_ + r) * D_ + d) * C_ + c0 + m0) = w;
        }
    }
}

// ---------------------------------------------------------------------------
// Attention logits.  128x128 tile, 256 threads, K split 8-way (1024 blocks).
// ---------------------------------------------------------------------------
__global__ __launch_bounds__(256) void logits_mfma(
    const ushort* __restrict__ qb, const ushort* __restrict__ kb,
    float* __restrict__ partial)
{
    __shared__ __align__(16) ushort S[24576];
    BUFS3;
    const int id = ((blockIdx.x & 7) * 128) + (blockIdx.x >> 3);
    const int sub = id & 15;
    const int j0 = (sub & 3) * 128;         // j fastest: 4 blocks share q panel
    const int i0 = (sub >> 2) * 128;
    const int hks = id >> 4;                // 0..63
    const int h = hks >> 3, ks = hks & 7;
    PREAMBLE(wid >> 1, wid & 1);

    const ushort* Ab = qb + (((size_t)h * R_ + ks * 64) * C_ + i0) * D_;
    const ushort* Bb = kb + (((size_t)h * R_ + ks * 64) * C_ + j0) * D_;

#define LSTG(i, Abuf, Bbuf) {                                   \
    const ushort* Ai = Ab + (size_t)(i) * (C_ * D_);            \
    const ushort* Bi = Bb + (size_t)(i) * (C_ * D_);            \
    SCH(Ai, D_, Abuf, t); SCH(Ai, D_, Abuf, t + 256);           \
    SCH(Bi, D_, Bbuf, t); SCH(Bi, D_, Bbuf, t + 256); }
    DBUFT(LSTG, 64);

    float* dst = partial + ((size_t)ks * H_ + h) * C_ * C_;
    #pragma unroll
    for (int fm = 0; fm < 4; ++fm)
        #pragma unroll
        for (int rg = 0; rg < 4; ++rg) {
            const int i = i0 + wm * 64 + fm * 16 + lhi * 4 + rg;
            #pragma unroll
            for (int fn = 0; fn < 4; ++fn) {
                const int j = j0 + wn * 64 + fn * 16 + l15;
                dst[(size_t)i * C_ + j] = acc[fm][fn][rg];
            }
        }
}

// ---------------------------------------------------------------------------
// Sum 8 K-split partials + i-axis mask + softmax over j.
// ---------------------------------------------------------------------------
__global__ __launch_bounds__(256) void softmax_kernel(
    const float* __restrict__ partial, const float* __restrict__ mask,
    float* __restrict__ probs, ushort* __restrict__ Pb)
{
    const int hi = blockIdx.x;
    const int i = hi & 511;
    const int t = threadIdx.x;
    const size_t base = (size_t)hi * C_;
    const size_t stride = (size_t)H_ * C_ * C_;
    float v0 = 0.f, v1 = 0.f;
    #pragma unroll
    for (int ksp = 0; ksp < 8; ++ksp) {
        v0 += partial[ksp * stride + base + t];
        v1 += partial[ksp * stride + base + t + 256];
    }
    const float mi = mask[i];
    const float keep = 1.0f - mi;
    v0 = v0 * keep + mi * (-10000.0f);
    v1 = v1 * keep + mi * (-10000.0f);

    float m = fmaxf(v0, v1);
    #pragma unroll
    for (int off = 32; off > 0; off >>= 1) m = fmaxf(m, __shfl_xor(m, off));
    __shared__ float red[4];
    if ((t & 63) == 0) red[t >> 6] = m;
    __syncthreads();
    m = fmaxf(fmaxf(red[0], red[1]), fmaxf(red[2], red[3]));

    const float e0 = expf(v0 - m), e1 = expf(v1 - m);
    float s = e0 + e1;
    #pragma unroll
    for (int off = 32; off > 0; off >>= 1) s += __shfl_xor(s, off);
    __syncthreads();
    if ((t & 63) == 0) red[t >> 6] = s;
    __syncthreads();
    s = red[0] + red[1] + red[2] + red[3];

    const float inv = 1.0f / s;
    const float p0 = e0 * inv, p1 = e1 * inv;
    probs[base + t] = p0;
    probs[base + t + 256] = p1;
    Pb[base + t] = f2bf(p0);
    Pb[base + t + 256] = f2bf(p1);
}

// ---------------------------------------------------------------------------
// Context.  128x128 tile, 256 threads, 4096 blocks (one head per XCD).
// ---------------------------------------------------------------------------
__global__ __launch_bounds__(256) void context_mfma(
    const ushort* __restrict__ Pb, const ushort* __restrict__ vb,
    ushort* __restrict__ ctxb)
{
    __shared__ __align__(16) ushort S[24576];
    BUFS3;
    const int id = ((blockIdx.x & 7) * 512) + (blockIdx.x >> 3);
    const int i0 = (id & 3) * 128;          // i fastest: 4 blocks share vb panel
    const int n0 = ((id >> 2) & 127) * 128;
    const int h = id >> 9;
    PREAMBLE(wid >> 1, wid & 1);

    const ushort* Ab = Pb + ((size_t)h * C_ + i0) * C_;
    const ushort* Bb = vb + ((size_t)h * R_ * D_ + n0) * C_;

#define CSTG(i, Abuf, Bbuf) {                                   \
    const ushort* Ai = Ab + (i) * 32;                           \
    const ushort* Bi = Bb + (i) * 32;                           \
    SCH(Ai, C_, Abuf, t); SCH(Ai, C_, Abuf, t + 256);           \
    SCH(Bi, C_, Bbuf, t); SCH(Bi, C_, Bbuf, t + 256); }
    DBUFT(CSTG, 16);
    __syncthreads();   // staging reads done before repack alias

    #pragma unroll
    for (int fm = 0; fm < 4; ++fm)
        #pragma unroll
        for (int fn = 0; fn < 4; ++fn)
            #pragma unroll
            for (int rg = 0; rg < 4; ++rg) {
                const int m = wm * 64 + fm * 16 + lhi * 4 + rg;
                const int n = wn * 64 + fn * 16 + l15;
                S[m * RP + n] = f2bf(acc[fm][fn][rg]);
            }
    __syncthreads();

    #pragma unroll
    for (int c = 0; c < 8; ++c) {
        const int idx = t + 256 * c;
        const int mrow = idx >> 4, nl = (idx & 15) * 8;
        uint4 w = *(const uint4*)(S + mrow * RP + nl);
        const int n = n0 + nl;
        const int rr = n >> 5, d = n & 31;
        const size_t rc = (size_t)rr * C_ + i0 + mrow;
        *(uint4*)(ctxb + rc * E_ + h * D_ + d) = w;
    }
}

// ---------------------------------------------------------------------------
// Output projection.  128x128 tile, 256 threads, 4096 blocks, fp32 out.
// ---------------------------------------------------------------------------
__global__ __launch_bounds__(256) void out_proj_mfma(
    const ushort* __restrict__ ctxb, const ushort* __restrict__ WoT,
    const float* __restrict__ bo, float* __restrict__ out)
{
    __shared__ __align__(16) ushort S[24576];
    BUFS3;
    float* Sf = (float*)S;                  // 128 x 68 fp32 repack (aliases)
    const int id = ((blockIdx.x & 7) * 512) + (blockIdx.x >> 3);
    const int n0 = (id & 1) * 128;
    const int rc0 = (id >> 1) * 128;
    PREAMBLE(wid >> 1, wid & 1);

    const ushort* Ab = ctxb + (size_t)rc0 * E_;
    const ushort* Bb = WoT + (size_t)n0 * E_;

#define OSTG(i, Abuf, Bbuf) {                                   \
    const ushort* Ai = Ab + (i) * 32;                           \
    const ushort* Bi = Bb + (i) * 32;                           \
    SCH(Ai, E_, Abuf, t); SCH(Ai, E_, Abuf, t + 256);           \
    SCH(Bi, E_, Bbuf, t); SCH(Bi, E_, Bbuf, t + 256); }
    DBUFT(OSTG, 8);
    __syncthreads();   // staging reads done before repack alias

    float bvv[4];
    #pragma unroll
    for (int fn = 0; fn < 4; ++fn)
        bvv[fn] = bo[n0 + wn * 64 + fn * 16 + l15];

    #pragma unroll
    for (int p = 0; p < 2; ++p) {
        #pragma unroll
        for (int fm = 0; fm < 4; ++fm)
            #pragma unroll
            for (int fh = 0; fh < 2; ++fh) {
                const int fn = 2 * p + fh;
                #pragma unroll
                for (int rg = 0; rg < 4; ++rg) {
                    const int m = wm * 64 + fm * 16 + lhi * 4 + rg;
                    const int s = wn * 32 + fh * 16 + l15;
                    Sf[m * 68 + s] = acc[fm][fn][rg] + bvv[fn];
                }
            }
        __syncthreads();
        #pragma unroll
        for (int c = 0; c < 8; ++c) {
            const int idx = t + 256 * c;
            const int row = idx >> 4, s0 = (idx & 15) * 4;
            float4 w = *(const float4*)(Sf + row * 68 + s0);
            const int ncol = n0 + (s0 >> 5) * 64 + (2 * p + ((s0 >> 4) & 1)) * 16 + (s0 & 15);
            *(float4*)(out + ((size_t)rc0 + row) * E_ + ncol) = w;
        }
        __syncthreads();
    }
}

// ---------------------------------------------------------------------------
extern "C" void kernel_launch(void* const* d_in, const int* in_sizes, int n_in,
                              void* d_out, int out_size, void* d_ws, size_t ws_size,
                              hipStream_t stream)
{
    const float* x    = (const float*)d_in[0];
    const float* mask = (const float*)d_in[1];
    const float* Wq   = (const float*)d_in[2];
    const float* bq   = (const float*)d_in[3];
    const float* Wk   = (const float*)d_in[4];
    const float* bk   = (const float*)d_in[5];
    const float* Wv   = (const float*)d_in[6];
    const float* bv   = (const float*)d_in[7];
    const float* Wo   = (const float*)d_in[8];
    const float* bo   = (const float*)d_in[9];

    float* out   = (float*)d_out;                       // [R,C,E] fp32
    float* probs = out + (size_t)RC_ * E_;              // [H,C,C] fp32

    char* ws = (char*)d_ws;
    ushort* qb      = (ushort*)(ws);                    // 128 MB  [h][r][c][d]
    ushort* kb      = (ushort*)(ws + 134217728ull);     // 128 MB  [h][r][c][d]
    ushort* vb      = (ushort*)(ws + 268435456ull);     // 128 MB  [h][r][d][c]
    ushort* ctxb    = (ushort*)(ws + 402653184ull);     // 128 MB  [rc][e]
    float*  partial = (float*)(ws + 536870912ull);      // 64 MB   [8][h][i][j]
    ushort* Pb      = (ushort*)(ws + 603979776ull);     // 4 MB    [h][i][j]
    ushort* WTqkv   = (ushort*)(ws + 608174080ull);     // 384 KB
    ushort* WoT     = (ushort*)(ws + 608567296ull);     // 128 KB
    ushort* xb      = (ushort*)(ws + 608700416ull);     // 128 MB  [rc][e]

    convert_x<<<16384, 256, 0, stream>>>(x, xb);
    convert_w<<<1024, 256, 0, stream>>>(Wq, Wk, Wv, Wo, WTqkv, WoT);
    qkv_mfma<<<12288, 256, 0, stream>>>(xb, WTqkv, bq, bk, bv, mask, qb, kb, vb);
    logits_mfma<<<1024, 256, 0, stream>>>(qb, kb, partial);
    softmax_kernel<<<4096, 256, 0, stream>>>(partial, mask, probs, Pb);
    context_mfma<<<4096, 256, 0, stream>>>(Pb, vb, ctxb);
    out_proj_mfma<<<4096, 256, 0, stream>>>(ctxb, WoT, bo, out);
}

// Round 13
// 614.114 us; speedup vs baseline: 1.3972x; 1.0208x over previous
//
#include <hip/hip_runtime.h>
#include <math.h>

#define R_ 512
#define C_ 512
#define E_ 256
#define H_ 8
#define D_ 32
#define RC_ (R_*C_)   // 262144
#define RP 136        // repack pitch (ushorts)

typedef __attribute__((ext_vector_type(8))) short bf16x8;
typedef __attribute__((ext_vector_type(4))) float f32x4;

__device__ __forceinline__ ushort f2bf(float f) {
    union { float f; unsigned u; } v; v.f = f;
    unsigned r = v.u + 0x7FFFu + ((v.u >> 16) & 1u);   // RNE
    return (ushort)(r >> 16);
}
__device__ __forceinline__ float bf2f(ushort u) {
    union { unsigned u; float f; } v; v.u = ((unsigned)u) << 16;
    return v.f;
}
// packed f32x2 -> bf16x2 (T12 primitive; RNE on gfx950)
__device__ __forceinline__ unsigned cvtpk(float lo, float hi) {
    unsigned r;
    asm("v_cvt_pk_bf16_f32 %0, %1, %2" : "=v"(r) : "v"(lo), "v"(hi));
    return r;
}

// 16B global->LDS direct copy (lane-linear dest), fallback = reg staging.
__device__ __forceinline__ void gll16(const ushort* g, ushort* l) {
#if __has_builtin(__builtin_amdgcn_global_load_lds)
    __builtin_amdgcn_global_load_lds(
        (const __attribute__((address_space(1))) unsigned*)(unsigned long long)g,
        (__attribute__((address_space(3))) unsigned*)(unsigned)(unsigned long long)l,
        16, 0, 0);
#else
    *(uint4*)l = *(const uint4*)g;
#endif
}

// Stage one 16B chunk f of a [rows][32-ushort] bf16 tile.  Source slot
// XOR-swizzled with (row>>1)&3 (verified r7).  LDS dest lane-linear.
#define SCH(gbase, stride, lds, f)                                               \
    gll16((gbase) + (size_t)((f) >> 2) * (stride)                                \
              + (((((f) & 3) ^ ((((f) >> 2) >> 1) & 3))) << 3),                  \
          (lds) + (f) * 8)

// --- Fenced sync primitives (validated r11/r12: rule #18 double-fence).
#define SCHED0   __builtin_amdgcn_sched_barrier(0)
#define ABAR     __builtin_amdgcn_s_barrier()
#define VMCNT(N) asm volatile("s_waitcnt vmcnt(" #N ")" ::: "memory")
#define LGKM0    asm volatile("s_waitcnt lgkmcnt(0)" ::: "memory")
#define SYNC_IN(N) do { VMCNT(N); SCHED0; ABAR; SCHED0; } while (0)
#define SYNC_OUT   do { LGKM0; SCHED0; ABAR; SCHED0; } while (0)

// Per-wave 64x64 output, 16x16x32 bf16 MFMA, K=32 per step, 32-ushort rows.
#define PREAMBLE(WM, WN)                                \
    const int t = threadIdx.x;                          \
    const int wid = t >> 6, l = t & 63;                 \
    const int wm = (WM), wn = (WN);                     \
    const int l15 = l & 15, lhi = l >> 4;               \
    const int swz8 = (lhi ^ ((l15 >> 1) & 3)) * 8;      \
    f32x4 acc[4][4];                                    \
    _Pragma("unroll")                                   \
    for (int a_ = 0; a_ < 4; ++a_)                      \
        _Pragma("unroll")                               \
        for (int b_ = 0; b_ < 4; ++b_)                  \
            acc[a_][b_] = (f32x4){0.f, 0.f, 0.f, 0.f};

#define MFMA_STEP(As, Bs)                                                        \
    {                                                                            \
        bf16x8 af_[4], bf_[4];                                                   \
        _Pragma("unroll")                                                        \
        for (int f_ = 0; f_ < 4; ++f_) {                                         \
            af_[f_] = *(const bf16x8*)((As) + (wm*64 + f_*16 + l15)*32 + swz8);  \
            bf_[f_] = *(const bf16x8*)((Bs) + (wn*64 + f_*16 + l15)*32 + swz8);  \
        }                                                                        \
        _Pragma("unroll")                                                        \
        for (int m_ = 0; m_ < 4; ++m_)                                           \
            _Pragma("unroll")                                                    \
            for (int n_ = 0; n_ < 4; ++n_)                                       \
                acc[m_][n_] = __builtin_amdgcn_mfma_f32_16x16x32_bf16(           \
                    af_[m_], bf_[n_], acc[m_][n_], 0, 0, 0);                     \
    }

// Triple-buffered K-loop, ONE fenced barrier per step, prefetch distance 2
// (validated r12).  Requires A0..A2/B0..B2; each STG = 4 gll16/thread.
#define DBUFT(STG, NIT)                                                          \
    STG(0, A0, B0); STG(1, A1, B1);                                              \
    _Pragma("unroll")                                                            \
    for (int s = 0; s < (NIT); ++s) {                                            \
        if (s < (NIT) - 1) { VMCNT(4); } else { VMCNT(0); }                      \
        SCHED0; ABAR; SCHED0;                                                    \
        if (s + 2 < (NIT)) {                                                     \
            if (((s + 2) % 3) == 0)      { STG(s + 2, A0, B0); }                 \
            else if (((s + 2) % 3) == 1) { STG(s + 2, A1, B1); }                 \
            else                         { STG(s + 2, A2, B2); }                 \
        }                                                                        \
        if ((s % 3) == 0)      { MFMA_STEP(A0, B0); }                            \
        else if ((s % 3) == 1) { MFMA_STEP(A1, B1); }                            \
        else                   { MFMA_STEP(A2, B2); }                            \
    }

#define BUFS3 ushort* A0 = S;          ushort* B0 = S + 4096;                    \
              ushort* A1 = S + 8192;   ushort* B1 = S + 12288;                   \
              ushort* A2 = S + 16384;  ushort* B2 = S + 20480;

// ---------------------------------------------------------------------------
// Weights -> n-major bf16.
// ---------------------------------------------------------------------------
__global__ __launch_bounds__(256) void convert_w(
    const float* __restrict__ Wq, const float* __restrict__ Wk,
    const float* __restrict__ Wv, const float* __restrict__ Wo,
    ushort* __restrict__ WTqkv, ushort* __restrict__ WoT)
{
    const int id = blockIdx.x;      // 0..1023
    const int matn = id >> 8;
    const int n = id & 255;
    const int k = threadIdx.x;
    const float* W = (matn == 0) ? Wq : (matn == 1) ? Wk : (matn == 2) ? Wv : Wo;
    ushort v = f2bf(W[(size_t)k * E_ + n]);
    if (matn < 3) WTqkv[((size_t)matn * E_ + n) * E_ + k] = v;
    else          WoT[(size_t)n * E_ + k] = v;
}

// ---------------------------------------------------------------------------
// Fused QKV projection, conversion FUSED (no separate convert_x pass).
// A staged as fp32 via gll16 ([128][32 f32], 16KB/buf, chunk key (row&3)<<1
// on 16B chunks — pair-preserving involution); converted to bf16 at fragment
// read with v_cvt_pk_bf16_f32 (2 elems/inst).  B staged bf16 as before.
// 2-buffer fenced DBUFC (r11-validated), VMCNT(6) counted.  12288 blocks x
// 256 thr (4 waves 2x2), XCD-chunked, nt fastest.  Epilogue unchanged.
// ---------------------------------------------------------------------------
__global__ __launch_bounds__(256) void qkv_mfma(
    const float* __restrict__ x, const ushort* __restrict__ WT,
    const float* __restrict__ bq, const float* __restrict__ bk,
    const float* __restrict__ bv, const float* __restrict__ mask,
    ushort* __restrict__ qb, ushort* __restrict__ kb, ushort* __restrict__ vb)
{
    __shared__ __align__(16) ushort S[24576];   // 48KB; repack aliases front
    float*  Af0 = (float*)S;            // 16KB  [128][32] f32
    float*  Af1 = (float*)(S + 8192);   // 16KB
    ushort* B0  = S + 16384;            // 8KB   [128][32] bf16
    ushort* B1  = S + 20480;            // 8KB
    const int id = ((blockIdx.x & 7) * 1536) + (blockIdx.x >> 3);
    const int nt = id % 6;
    const int rc0 = (id / 6) * 128;
    const int t = threadIdx.x;
    const int wid = t >> 6, l = t & 63;
    const int wm = wid >> 1, wn = wid & 1;
    const int l15 = l & 15, lhi = l >> 4;
    const int swz8 = (lhi ^ ((l15 >> 1) & 3)) * 8;   // B read (bf16 rows)
    const int pA   = (lhi ^ (l15 & 3)) * 8;          // A read (f32 rows)
    f32x4 acc[4][4];
    #pragma unroll
    for (int a_ = 0; a_ < 4; ++a_)
        #pragma unroll
        for (int b_ = 0; b_ < 4; ++b_)
            acc[a_][b_] = (f32x4){0.f, 0.f, 0.f, 0.f};

    const float*  Ab = x + (size_t)rc0 * E_;
    const ushort* Bb = WT + (size_t)nt * 128 * E_;

// A: 1024 16B-chunks (4/thread); row=f>>3, source chunk (f&7)^((row&3)<<1).
// B: 512 chunks (2/thread), standard SCH.  6 gll16/thread/step total.
#define QSTG(i, Af, Bbuf) {                                                      \
    _Pragma("unroll")                                                            \
    for (int c2 = 0; c2 < 4; ++c2) {                                             \
        const int f = t + 256 * c2;                                              \
        const int row = f >> 3;                                                  \
        const int cc = (f & 7) ^ ((row & 3) << 1);                               \
        gll16((const ushort*)(Ab + (size_t)row * E_ + (i) * 32 + cc * 4),        \
              (ushort*)((Af) + f * 4));                                          \
    }                                                                            \
    const ushort* Bi = Bb + (i) * 32;                                            \
    SCH(Bi, E_, Bbuf, t); SCH(Bi, E_, Bbuf, t + 256); }

// Fragment read: A fp32 -> cvt_pk -> bf16x8; B as usual; 16 MFMA.
#define QMFMA(Af, Bs) {                                                          \
    bf16x8 af_[4], bf_[4];                                                       \
    _Pragma("unroll")                                                            \
    for (int f_ = 0; f_ < 4; ++f_) {                                             \
        const float* ap_ = (Af) + (wm*64 + f_*16 + l15) * 32 + pA;               \
        float4 xa_ = *(const float4*)ap_;                                        \
        float4 xc_ = *(const float4*)(ap_ + 4);                                  \
        union { unsigned u[4]; bf16x8 v; } pk_;                                  \
        pk_.u[0] = cvtpk(xa_.x, xa_.y); pk_.u[1] = cvtpk(xa_.z, xa_.w);          \
        pk_.u[2] = cvtpk(xc_.x, xc_.y); pk_.u[3] = cvtpk(xc_.z, xc_.w);          \
        af_[f_] = pk_.v;                                                         \
        bf_[f_] = *(const bf16x8*)((Bs) + (wn*64 + f_*16 + l15)*32 + swz8);      \
    }                                                                            \
    _Pragma("unroll")                                                            \
    for (int m_ = 0; m_ < 4; ++m_)                                               \
        _Pragma("unroll")                                                        \
        for (int n_ = 0; n_ < 4; ++n_)                                           \
            acc[m_][n_] = __builtin_amdgcn_mfma_f32_16x16x32_bf16(               \
                af_[m_], bf_[n_], acc[m_][n_], 0, 0, 0); }

    // 8 K-steps, 2-buffer fenced DBUFC (r11 pattern), counted VMCNT(6).
    QSTG(0, Af0, B0);
    #pragma unroll
    for (int itp = 0; itp < 4; ++itp) {
        QSTG(2*itp + 1, Af1, B1);
        SYNC_IN(6);
        QMFMA(Af0, B0);
        SYNC_OUT;
        if (itp < 3) { QSTG(2*itp + 2, Af0, B0); SYNC_IN(6); }
        else         { SYNC_IN(0); }
        QMFMA(Af1, B1);
        SYNC_OUT;
    }

    const int proj = nt >> 1;
    const float* bias = (proj == 0) ? bq : (proj == 1) ? bk : bv;
    float bvv[4];
    #pragma unroll
    for (int fn = 0; fn < 4; ++fn)
        bvv[fn] = bias[(nt * 128 + wn * 64 + fn * 16 + l15) & 255];

    // repack: q/k as [c][e], v as [e][c]
    #pragma unroll
    for (int fm = 0; fm < 4; ++fm)
        #pragma unroll
        for (int fn = 0; fn < 4; ++fn)
            #pragma unroll
            for (int rg = 0; rg < 4; ++rg) {
                const int m = wm * 64 + fm * 16 + lhi * 4 + rg;
                const int n = wn * 64 + fn * 16 + l15;
                const ushort val = f2bf(acc[fm][fn][rg] + bvv[fn]);
                if (proj < 2) S[m * RP + n] = val;
                else          S[n * RP + m] = val;
            }
    __syncthreads();

    const int r = rc0 >> 9, c0 = rc0 & 511;
    if (proj < 2) {
        ushort* dst = (proj == 0) ? qb : kb;
        #pragma unroll
        for (int c = 0; c < 8; ++c) {
            const int idx = t + 256 * c;
            const int mrow = idx >> 4, ne = (idx & 15) * 8;
            uint4 w = *(const uint4*)(S + mrow * RP + ne);
            if (proj == 0) {   // q: * 1/128 * (1-mask)
                const float sk = 0.0078125f * (1.0f - mask[rc0 + mrow]);
                ushort* ws = (ushort*)&w;
                #pragma unroll
                for (int jj = 0; jj < 8; ++jj) ws[jj] = f2bf(bf2f(ws[jj]) * sk);
            }
            const int e = (nt & 1) * 128 + ne, h = e >> 5, d = e & 31;
            *(uint4*)(dst + ((((size_t)h * R_ + r) * C_) + c0 + mrow) * D_ + d) = w;
        }
    } else {
        #pragma unroll
        for (int c = 0; c < 8; ++c) {
            const int idx = t + 256 * c;
            const int nrow = idx >> 4, m0 = (idx & 15) * 8;
            uint4 w = *(const uint4*)(S + nrow * RP + m0);
            const int e = (nt & 1) * 128 + nrow, h = e >> 5, d = e & 31;
            *(uint4*)(vb + (((size_t)h * R_ + r) * D_ + d) * C_ + c0 + m0) = w;
        }
    }
#undef QSTG
#undef QMFMA
}

// ---------------------------------------------------------------------------
// Attention logits.  128x128 tile, 256 threads, K split 8-way (1024 blocks).
// ---------------------------------------------------------------------------
__global__ __launch_bounds__(256) void logits_mfma(
    const ushort* __restrict__ qb, const ushort* __restrict__ kb,
    float* __restrict__ partial)
{
    __shared__ __align__(16) ushort S[24576];
    BUFS3;
    const int id = ((blockIdx.x & 7) * 128) + (blockIdx.x >> 3);
    const int sub = id & 15;
    const int j0 = (sub & 3) * 128;         // j fastest: 4 blocks share q panel
    const int i0 = (sub >> 2) * 128;
    const int hks = id >> 4;                // 0..63
    const int h = hks >> 3, ks = hks & 7;
    PREAMBLE(wid >> 1, wid & 1);

    const ushort* Ab = qb + (((size_t)h * R_ + ks * 64) * C_ + i0) * D_;
    const ushort* Bb = kb + (((size_t)h * R_ + ks * 64) * C_ + j0) * D_;

#define LSTG(i, Abuf, Bbuf) {                                   \
    const ushort* Ai = Ab + (size_t)(i) * (C_ * D_);            \
    const ushort* Bi = Bb + (size_t)(i) * (C_ * D_);            \
    SCH(Ai, D_, Abuf, t); SCH(Ai, D_, Abuf, t + 256);           \
    SCH(Bi, D_, Bbuf, t); SCH(Bi, D_, Bbuf, t + 256); }
    DBUFT(LSTG, 64);

    float* dst = partial + ((size_t)ks * H_ + h) * C_ * C_;
    #pragma unroll
    for (int fm = 0; fm < 4; ++fm)
        #pragma unroll
        for (int rg = 0; rg < 4; ++rg) {
            const int i = i0 + wm * 64 + fm * 16 + lhi * 4 + rg;
            #pragma unroll
            for (int fn = 0; fn < 4; ++fn) {
                const int j = j0 + wn * 64 + fn * 16 + l15;
                dst[(size_t)i * C_ + j] = acc[fm][fn][rg];
            }
        }
}

// ---------------------------------------------------------------------------
// Sum 8 K-split partials + i-axis mask + softmax over j.
// ---------------------------------------------------------------------------
__global__ __launch_bounds__(256) void softmax_kernel(
    const float* __restrict__ partial, const float* __restrict__ mask,
    float* __restrict__ probs, ushort* __restrict__ Pb)
{
    const int hi = blockIdx.x;
    const int i = hi & 511;
    const int t = threadIdx.x;
    const size_t base = (size_t)hi * C_;
    const size_t stride = (size_t)H_ * C_ * C_;
    float v0 = 0.f, v1 = 0.f;
    #pragma unroll
    for (int ksp = 0; ksp < 8; ++ksp) {
        v0 += partial[ksp * stride + base + t];
        v1 += partial[ksp * stride + base + t + 256];
    }
    const float mi = mask[i];
    const float keep = 1.0f - mi;
    v0 = v0 * keep + mi * (-10000.0f);
    v1 = v1 * keep + mi * (-10000.0f);

    float m = fmaxf(v0, v1);
    #pragma unroll
    for (int off = 32; off > 0; off >>= 1) m = fmaxf(m, __shfl_xor(m, off));
    __shared__ float red[4];
    if ((t & 63) == 0) red[t >> 6] = m;
    __syncthreads();
    m = fmaxf(fmaxf(red[0], red[1]), fmaxf(red[2], red[3]));

    const float e0 = expf(v0 - m), e1 = expf(v1 - m);
    float s = e0 + e1;
    #pragma unroll
    for (int off = 32; off > 0; off >>= 1) s += __shfl_xor(s, off);
    __syncthreads();
    if ((t & 63) == 0) red[t >> 6] = s;
    __syncthreads();
    s = red[0] + red[1] + red[2] + red[3];

    const float inv = 1.0f / s;
    const float p0 = e0 * inv, p1 = e1 * inv;
    probs[base + t] = p0;
    probs[base + t + 256] = p1;
    Pb[base + t] = f2bf(p0);
    Pb[base + t + 256] = f2bf(p1);
}

// ---------------------------------------------------------------------------
// Context.  128x128 tile, 256 threads, 4096 blocks (one head per XCD).
// ---------------------------------------------------------------------------
__global__ __launch_bounds__(256) void context_mfma(
    const ushort* __restrict__ Pb, const ushort* __restrict__ vb,
    ushort* __restrict__ ctxb)
{
    __shared__ __align__(16) ushort S[24576];
    BUFS3;
    const int id = ((blockIdx.x & 7) * 512) + (blockIdx.x >> 3);
    const int i0 = (id & 3) * 128;          // i fastest: 4 blocks share vb panel
    const int n0 = ((id >> 2) & 127) * 128;
    const int h = id >> 9;
    PREAMBLE(wid >> 1, wid & 1);

    const ushort* Ab = Pb + ((size_t)h * C_ + i0) * C_;
    const ushort* Bb = vb + ((size_t)h * R_ * D_ + n0) * C_;

#define CSTG(i, Abuf, Bbuf) {                                   \
    const ushort* Ai = Ab + (i) * 32;                           \
    const ushort* Bi = Bb + (i) * 32;                           \
    SCH(Ai, C_, Abuf, t); SCH(Ai, C_, Abuf, t + 256);           \
    SCH(Bi, C_, Bbuf, t); SCH(Bi, C_, Bbuf, t + 256); }
    DBUFT(CSTG, 16);
    __syncthreads();   // staging reads done before repack alias

    #pragma unroll
    for (int fm = 0; fm < 4; ++fm)
        #pragma unroll
        for (int fn = 0; fn < 4; ++fn)
            #pragma unroll
            for (int rg = 0; rg < 4; ++rg) {
                const int m = wm * 64 + fm * 16 + lhi * 4 + rg;
                const int n = wn * 64 + fn * 16 + l15;
                S[m * RP + n] = f2bf(acc[fm][fn][rg]);
            }
    __syncthreads();

    #pragma unroll
    for (int c = 0; c < 8; ++c) {
        const int idx = t + 256 * c;
        const int mrow = idx >> 4, nl = (idx & 15) * 8;
        uint4 w = *(const uint4*)(S + mrow * RP + nl);
        const int n = n0 + nl;
        const int rr = n >> 5, d = n & 31;
        const size_t rc = (size_t)rr * C_ + i0 + mrow;
        *(uint4*)(ctxb + rc * E_ + h * D_ + d) = w;
    }
}

// ---------------------------------------------------------------------------
// Output projection.  128x128 tile, 256 threads, 4096 blocks, fp32 out.
// ---------------------------------------------------------------------------
__global__ __launch_bounds__(256) void out_proj_mfma(
    const ushort* __restrict__ ctxb, const ushort* __restrict__ WoT,
    const float* __restrict__ bo, float* __restrict__ out)
{
    __shared__ __align__(16) ushort S[24576];
    BUFS3;
    float* Sf = (float*)S;                  // 128 x 68 fp32 repack (aliases)
    const int id = ((blockIdx.x & 7) * 512) + (blockIdx.x >> 3);
    const int n0 = (id & 1) * 128;
    const int rc0 = (id >> 1) * 128;
    PREAMBLE(wid >> 1, wid & 1);

    const ushort* Ab = ctxb + (size_t)rc0 * E_;
    const ushort* Bb = WoT + (size_t)n0 * E_;

#define OSTG(i, Abuf, Bbuf) {                                   \
    const ushort* Ai = Ab + (i) * 32;                           \
    const ushort* Bi = Bb + (i) * 32;                           \
    SCH(Ai, E_, Abuf, t); SCH(Ai, E_, Abuf, t + 256);           \
    SCH(Bi, E_, Bbuf, t); SCH(Bi, E_, Bbuf, t + 256); }
    DBUFT(OSTG, 8);
    __syncthreads();   // staging reads done before repack alias

    float bvv[4];
    #pragma unroll
    for (int fn = 0; fn < 4; ++fn)
        bvv[fn] = bo[n0 + wn * 64 + fn * 16 + l15];

    #pragma unroll
    for (int p = 0; p < 2; ++p) {
        #pragma unroll
        for (int fm = 0; fm < 4; ++fm)
            #pragma unroll
            for (int fh = 0; fh < 2; ++fh) {
                const int fn = 2 * p + fh;
                #pragma unroll
                for (int rg = 0; rg < 4; ++rg) {
                    const int m = wm * 64 + fm * 16 + lhi * 4 + rg;
                    const int s = wn * 32 + fh * 16 + l15;
                    Sf[m * 68 + s] = acc[fm][fn][rg] + bvv[fn];
                }
            }
        __syncthreads();
        #pragma unroll
        for (int c = 0; c < 8; ++c) {
            const int idx = t + 256 * c;
            const int row = idx >> 4, s0 = (idx & 15) * 4;
            float4 w = *(const float4*)(Sf + row * 68 + s0);
            const int ncol = n0 + (s0 >> 5) * 64 + (2 * p + ((s0 >> 4) & 1)) * 16 + (s0 & 15);
            *(float4*)(out + ((size_t)rc0 + row) * E_ + ncol) = w;
        }
        __syncthreads();
    }
}

// ---------------------------------------------------------------------------
extern "C" void kernel_launch(void* const* d_in, const int* in_sizes, int n_in,
                              void* d_out, int out_size, void* d_ws, size_t ws_size,
                              hipStream_t stream)
{
    const float* x    = (const float*)d_in[0];
    const float* mask = (const float*)d_in[1];
    const float* Wq   = (const float*)d_in[2];
    const float* bq   = (const float*)d_in[3];
    const float* Wk   = (const float*)d_in[4];
    const float* bk   = (const float*)d_in[5];
    const float* Wv   = (const float*)d_in[6];
    const float* bv   = (const float*)d_in[7];
    const float* Wo   = (const float*)d_in[8];
    const float* bo   = (const float*)d_in[9];

    float* out   = (float*)d_out;                       // [R,C,E] fp32
    float* probs = out + (size_t)RC_ * E_;              // [H,C,C] fp32

    char* ws = (char*)d_ws;
    ushort* qb      = (ushort*)(ws);                    // 128 MB  [h][r][c][d]
    ushort* kb      = (ushort*)(ws + 134217728ull);     // 128 MB  [h][r][c][d]
    ushort* vb      = (ushort*)(ws + 268435456ull);     // 128 MB  [h][r][d][c]
    ushort* ctxb    = (ushort*)(ws + 402653184ull);     // 128 MB  [rc][e]
    float*  partial = (float*)(ws + 536870912ull);      // 64 MB   [8][h][i][j]
    ushort* Pb      = (ushort*)(ws + 603979776ull);     // 4 MB    [h][i][j]
    ushort* WTqkv   = (ushort*)(ws + 608174080ull);     // 384 KB
    ushort* WoT     = (ushort*)(ws + 608567296ull);     // 128 KB

    convert_w<<<1024, 256, 0, stream>>>(Wq, Wk, Wv, Wo, WTqkv, WoT);
    qkv_mfma<<<12288, 256, 0, stream>>>(x, WTqkv, bq, bk, bv, mask, qb, kb, vb);
    logits_mfma<<<1024, 256, 0, stream>>>(qb, kb, partial);
    softmax_kernel<<<4096, 256, 0, stream>>>(partial, mask, probs, Pb);
    context_mfma<<<4096, 256, 0, stream>>>(Pb, vb, ctxb);
    out_proj_mfma<<<4096, 256, 0, stream>>>(ctxb, WoT, bo, out);
}